// Round 12
// baseline (2722.014 us; speedup 1.0000x reference)
//
#include <hip/hip_runtime.h>
#include <cstdint>
#include <cstddef>

typedef __attribute__((ext_vector_type(8))) short short8;
typedef __attribute__((ext_vector_type(4))) float f32x4;

#define DEV static __device__ __forceinline__

#define PRED_ELEMS 19200000ULL   // 64*30*10000

// ---- workspace layout (bytes) ----
#define OFF_ENC   0ULL          // ushort [12544][2048] sorted enc bf16
#define OFF_ATT1  51380224ULL   // ushort [12544][512]
#define OFF_B1    64225280ULL   // ushort [2560][1024]  [Wd|0 ; Whh|Wih_e interleaved]
#define OFF_WFC   69468160ULL   // ushort [10016][512]  Wfc bf16, zero padded
#define OFF_WEB   79724544ULL   // ushort [512][2048]   We bf16
#define OFF_B0    81821696ULL   // ushort [1024][2048]  [Wh0;Wc0] (dead after k_h0c0)
#define OFF_HH    81821696ULL   // ushort [30][64][512] h history (reuses B0)
#define OFF_B2    86016000ULL   // ushort [2048][2048]  Wih ctx-part, interleaved rows
#define OFF_HX    94404608ULL   // ushort [64][1024]    [h | e_t] bf16
#define OFF_C     94535680ULL   // float  [64][512]
#define OFF_ATT2  94666752ULL   // float  [64][512]     (fallback only)
#define OFF_GEH   94797824ULL   // float  [64][2048]    gates from h,e (interleaved 4d+q)
#define OFF_SC    95322112ULL   // float  [64][196]     alpha (or raw scores in fallback)
#define OFF_CTX   95372288ULL   // ushort [64][2048]    fallback ctx (also meanb in setup)
#define OFF_META  95634432ULL   // int: idx[64] dec[64] nact[32] caps[64*31]
#define OFF_ENCW  96000000ULL   // ushort [12544][2048] enc @ Wih_ctx^T (j-interleaved)
#define ENCW_BYTES 51380224ULL

DEV float b2f(unsigned short u){ unsigned v = ((unsigned)u) << 16; float f; __builtin_memcpy(&f, &v, 4); return f; }
DEV unsigned short f2b(float x){ unsigned v; __builtin_memcpy(&v, &x, 4); unsigned r = v + 0x7fffu + ((v >> 16) & 1u); return (unsigned short)(r >> 16); }
DEV float sigm(float x){ return 1.0f / (1.0f + __expf(-x)); }
DEV float tanhf_fast(float x){ float e = __expf(2.0f * x); return 1.0f - 2.0f / (e + 1.0f); }

DEV void gload16(const void* g, void* l){
  __builtin_amdgcn_global_load_lds((const __attribute__((address_space(1))) unsigned int*)g,
                                   (__attribute__((address_space(3))) unsigned int*)l, 16, 0, 0);
}

// ---- LDS-staged 64x64 core (used only by one-time k_h0c0) ----
DEV void mm_core(const unsigned short* A, int ldA, int m0,
                 const unsigned short* Bm, int ldB, int n0,
                 int kIters, unsigned short* As, unsigned short* Bs, f32x4 acc[4])
{
  const int tid = threadIdx.x;
  const int lane = tid & 63, w = tid >> 6;
  const unsigned short* ga = A + (size_t)(m0 + lane) * ldA + w * 8;
  const unsigned short* gb = Bm + (size_t)(n0 + lane) * ldB + w * 8;
  unsigned short* la = As + w * 512;
  unsigned short* lb = Bs + w * 512;
  const int kb = lane >> 4, rr = lane & 15;
  for (int kk = 0; kk < kIters; ++kk) {
    gload16(ga, la); gload16(gb, lb);
    ga += 32; gb += 32;
    asm volatile("s_waitcnt vmcnt(0)" ::: "memory");
    __syncthreads();
    short8 bfr = *(const short8*)(Bs + (size_t)(kb * 64 + w * 16 + rr) * 8);
#pragma unroll
    for (int f = 0; f < 4; ++f) {
      short8 afr = *(const short8*)(As + (size_t)(kb * 64 + f * 16 + rr) * 8);
      acc[f] = __builtin_amdgcn_mfma_f32_16x16x32_bf16(afr, bfr, acc[f], 0, 0, 0);
    }
    __syncthreads();
  }
}

__global__ void k_meta(const int* __restrict__ caps, const int* __restrict__ lens, int* __restrict__ meta){
  int j = threadIdx.x;
  int lj = lens[j];
  int rank = 0;
  for (int k = 0; k < 64; ++k) { int lk = lens[k]; rank += (lk > lj) || (lk == lj && k < j); }
  meta[rank] = j; meta[64 + rank] = lj - 1;
  for (int t = 0; t < 31; ++t) meta[160 + rank * 31 + t] = caps[j * 31 + t];
  __syncthreads();
  if (j < 30) { int c = 0; for (int b = 0; b < 64; ++b) c += (meta[64 + b] > j); meta[128 + j] = c; }
}

__global__ __launch_bounds__(256) void k_encg(const float* __restrict__ enc, const int* __restrict__ meta, unsigned short* __restrict__ encb){
  int row = blockIdx.x; int b = row / 196, p = row % 196;
  const float* src = enc + ((size_t)meta[b] * 196 + p) * 2048;
  unsigned short* dst = encb + (size_t)row * 2048;
  int e0 = threadIdx.x * 8;
  short8 o;
#pragma unroll
  for (int j = 0; j < 8; ++j) o[j] = (short)f2b(src[e0 + j]);
  *(short8*)(dst + e0) = o;
}

__global__ __launch_bounds__(256) void k_wconv(const float* We, const float* Wh0, const float* Wc0,
                        const float* Wd, const float* Whh, const float* Wih, const float* Wfc,
                        unsigned short* Web, unsigned short* B0, unsigned short* B1,
                        unsigned short* Wfcb, unsigned short* B2){
  int bid = blockIdx.x, tid = threadIdx.x;
  if (bid < 512) {
    const float* s = We + (size_t)bid * 2048; unsigned short* d = Web + (size_t)bid * 2048;
    int e0 = tid * 8; short8 o;
#pragma unroll
    for (int j = 0; j < 8; ++j) o[j] = (short)f2b(s[e0 + j]);
    *(short8*)(d + e0) = o;
  } else if (bid < 1536) {
    int r = bid - 512;
    const float* s = (r < 512) ? (Wh0 + (size_t)r * 2048) : (Wc0 + (size_t)(r - 512) * 2048);
    unsigned short* d = B0 + (size_t)r * 2048;
    int e0 = tid * 8; short8 o;
#pragma unroll
    for (int j = 0; j < 8; ++j) o[j] = (short)f2b(s[e0 + j]);
    *(short8*)(d + e0) = o;
  } else if (bid < 3584) {   // B2: 2048 rows, j-interleaved (g = (j&3)*512 + (j>>2))
    int jr = bid - 1536; int g = (jr & 3) * 512 + (jr >> 2);
    const float* s = Wih + (size_t)g * 2560 + 512;
    unsigned short* d = B2 + (size_t)jr * 2048;
    int e0 = tid * 8; short8 o;
#pragma unroll
    for (int j = 0; j < 8; ++j) o[j] = (short)f2b(s[e0 + j]);
    *(short8*)(d + e0) = o;
  } else if (bid < 6144) {   // B1: 2560 rows
    int n = bid - 3584; unsigned short* d = B1 + (size_t)n * 1024;
    int k0 = tid * 4;
    if (n < 512) {
#pragma unroll
      for (int j = 0; j < 4; ++j) { int k = k0 + j; d[k] = (k < 512) ? f2b(Wd[(size_t)n * 512 + k]) : (unsigned short)0; }
    } else {
      int j2 = n - 512; int g = (j2 & 3) * 512 + (j2 >> 2);
#pragma unroll
      for (int j = 0; j < 4; ++j) { int k = k0 + j;
        d[k] = (k < 512) ? f2b(Whh[(size_t)g * 512 + k]) : f2b(Wih[(size_t)g * 2560 + (k - 512)]); }
    }
  } else {                   // Wfcb: 10016 rows
    int v = bid - 6144; unsigned short* d = Wfcb + (size_t)v * 512;
    int k0 = tid * 2;
#pragma unroll
    for (int j = 0; j < 2; ++j) d[k0 + j] = (v < 10000) ? f2b(Wfc[(size_t)v * 512 + k0 + j]) : (unsigned short)0;
  }
}

__global__ __launch_bounds__(256) void k_mean(const unsigned short* __restrict__ encb, unsigned short* __restrict__ meanb){
  int b = blockIdx.y, ch = blockIdx.x;
  int e = ch * 512 + threadIdx.x * 2;
  const unsigned short* ep = encb + (size_t)b * 196 * 2048 + e;
  float s0 = 0.f, s1 = 0.f;
  for (int p = 0; p < 196; ++p) {
    unsigned u = *(const unsigned*)(ep + (size_t)p * 2048);
    s0 += b2f((unsigned short)(u & 0xffff));
    s1 += b2f((unsigned short)(u >> 16));
  }
  const float inv = 1.0f / 196.0f;
  unsigned o = ((unsigned)f2b(s1 * inv) << 16) | f2b(s0 * inv);
  *(unsigned*)(meanb + (size_t)b * 2048 + e) = o;
}

__global__ __launch_bounds__(256) void k_h0c0(const unsigned short* meanb, const unsigned short* B0,
                      const float* bh0, const float* bc0, unsigned short* hx, float* cbuf){
  __shared__ __align__(16) unsigned short As[2048], Bs[2048];
  f32x4 acc[4];
#pragma unroll
  for (int f = 0; f < 4; ++f) acc[f] = (f32x4){0.f,0.f,0.f,0.f};
  int nt = blockIdx.x;
  mm_core(meanb, 2048, 0, B0, 2048, nt * 64, 64, As, Bs, acc);
  int lane = threadIdx.x & 63, w = threadIdx.x >> 6;
  int col = lane & 15, rhi = lane >> 4;
  int n = nt * 64 + w * 16 + col;
#pragma unroll
  for (int f = 0; f < 4; ++f)
#pragma unroll
    for (int r = 0; r < 4; ++r) {
      int b = f * 16 + rhi * 4 + r; float v = acc[f][r];
      if (n < 512) hx[(size_t)b * 1024 + n] = f2b(v + bh0[n]);
      else cbuf[(size_t)b * 512 + (n - 512)] = v + bc0[n - 512];
    }
}

__global__ void k_emb0(const float* __restrict__ Wemb, const int* __restrict__ meta, unsigned short* __restrict__ hx){
  int b = blockIdx.x;
  int cap = meta[160 + b * 31];
  for (int j = threadIdx.x; j < 512; j += 256)
    hx[(size_t)b * 1024 + 512 + j] = f2b(Wemb[(size_t)cap * 512 + j]);
}

// ---- att1: 128x128 tile GEMM with XCD-grouped block swizzle ----
__global__ __launch_bounds__(256) void k_att1(const unsigned short* __restrict__ encb,
                      const unsigned short* __restrict__ Web,
                      const float* __restrict__ be, unsigned short* __restrict__ att1b){
  __shared__ __align__(16) unsigned short As[2][4096], Bs[2][4096];
  int tid = threadIdx.x, lane = tid & 63, w = tid >> 6;
  int bid = blockIdx.x, mt, nt;
  if (bid < 384) { mt = (bid >> 5) * 8 + (bid & 7); nt = (bid >> 3) & 3; }
  else           { mt = 96 + ((bid - 384) >> 2);    nt = (bid - 384) & 3; }
  int wr = (w >> 1) * 64, wc = (w & 1) * 64;
  int rr = lane & 15, kb = lane >> 4;
  f32x4 acc[4][4];
#pragma unroll
  for (int f = 0; f < 4; ++f)
#pragma unroll
    for (int q = 0; q < 4; ++q) acc[f][q] = (f32x4){0.f,0.f,0.f,0.f};

  const unsigned short* gA = encb + (size_t)mt * 128 * 2048;
  const unsigned short* gB = Web + (size_t)nt * 128 * 2048;
  int L0 = tid, L1 = tid + 256;
  size_t s0 = (size_t)(L0 & 127) * 2048 + ((L0 >> 7) << 3);
  size_t s1 = (size_t)(L1 & 127) * 2048 + ((L1 >> 7) << 3);
  int d0 = (w * 64) * 8, d1 = (w * 64 + 256) * 8;

#define STAGE_A1(kk, bf) do { \
    gload16(gA + s0 + (size_t)(kk) * 32, &As[bf][d0]); \
    gload16(gB + s0 + (size_t)(kk) * 32, &Bs[bf][d0]); \
    gload16(gA + s1 + (size_t)(kk) * 32, &As[bf][d1]); \
    gload16(gB + s1 + (size_t)(kk) * 32, &Bs[bf][d1]); \
  } while (0)

  STAGE_A1(0, 0);
  __syncthreads();
  for (int kk = 0; kk < 64; ++kk) {
    int cur = kk & 1;
    if (kk < 63) STAGE_A1(kk + 1, cur ^ 1);
    short8 af[4], bq[4];
#pragma unroll
    for (int f = 0; f < 4; ++f)
      af[f] = *(const short8*)&As[cur][((kb << 7) + wr + f * 16 + rr) * 8];
#pragma unroll
    for (int q = 0; q < 4; ++q)
      bq[q] = *(const short8*)&Bs[cur][((kb << 7) + wc + q * 16 + rr) * 8];
#pragma unroll
    for (int f = 0; f < 4; ++f)
#pragma unroll
      for (int q = 0; q < 4; ++q)
        acc[f][q] = __builtin_amdgcn_mfma_f32_16x16x32_bf16(af[f], bq[q], acc[f][q], 0, 0, 0);
    __syncthreads();
  }
#undef STAGE_A1
  int col = lane & 15, rhi = lane >> 4;
#pragma unroll
  for (int q = 0; q < 4; ++q) {
    int n = nt * 128 + wc + q * 16 + col;
    float bev = be[n];
#pragma unroll
    for (int f = 0; f < 4; ++f)
#pragma unroll
      for (int r = 0; r < 4; ++r) {
        int m = mt * 128 + wr + f * 16 + rhi * 4 + r;
        att1b[(size_t)m * 512 + n] = f2b(acc[f][q][r] + bev);
      }
  }
}

// ---- encW = enc @ B2^T (one-time): XCD-grouped — all 16 n-tiles of one m-tile per XCD ----
__global__ __launch_bounds__(256) void k_encw(const unsigned short* __restrict__ encb,
                      const unsigned short* __restrict__ B2, unsigned short* __restrict__ encW){
  __shared__ __align__(16) unsigned short As[2][4096], Bs[2][4096];
  int tid = threadIdx.x, lane = tid & 63, w = tid >> 6;
  int xcd = blockIdx.x & 7, slot = blockIdx.x >> 3;
  int mtl = slot >> 4, nt = slot & 15;
  int mt = mtl * 8 + xcd;
  if (mt >= 98) return;
  int wr = (w >> 1) * 64, wc = (w & 1) * 64;
  int rr = lane & 15, kb = lane >> 4;
  f32x4 acc[4][4];
#pragma unroll
  for (int f = 0; f < 4; ++f)
#pragma unroll
    for (int q = 0; q < 4; ++q) acc[f][q] = (f32x4){0.f,0.f,0.f,0.f};

  const unsigned short* gA = encb + (size_t)mt * 128 * 2048;
  const unsigned short* gB = B2 + (size_t)nt * 128 * 2048;
  int L0 = tid, L1 = tid + 256;
  size_t s0 = (size_t)(L0 & 127) * 2048 + ((L0 >> 7) << 3);
  size_t s1 = (size_t)(L1 & 127) * 2048 + ((L1 >> 7) << 3);
  int d0 = (w * 64) * 8, d1 = (w * 64 + 256) * 8;

#define STAGE_W(kk, bf) do { \
    gload16(gA + s0 + (size_t)(kk) * 32, &As[bf][d0]); \
    gload16(gB + s0 + (size_t)(kk) * 32, &Bs[bf][d0]); \
    gload16(gA + s1 + (size_t)(kk) * 32, &As[bf][d1]); \
    gload16(gB + s1 + (size_t)(kk) * 32, &Bs[bf][d1]); \
  } while (0)

  STAGE_W(0, 0);
  __syncthreads();
  for (int kk = 0; kk < 64; ++kk) {
    int cur = kk & 1;
    if (kk < 63) STAGE_W(kk + 1, cur ^ 1);
    short8 af[4], bq[4];
#pragma unroll
    for (int f = 0; f < 4; ++f)
      af[f] = *(const short8*)&As[cur][((kb << 7) + wr + f * 16 + rr) * 8];
#pragma unroll
    for (int q = 0; q < 4; ++q)
      bq[q] = *(const short8*)&Bs[cur][((kb << 7) + wc + q * 16 + rr) * 8];
#pragma unroll
    for (int f = 0; f < 4; ++f)
#pragma unroll
      for (int q = 0; q < 4; ++q)
        acc[f][q] = __builtin_amdgcn_mfma_f32_16x16x32_bf16(af[f], bq[q], acc[f][q], 0, 0, 0);
    __syncthreads();
  }
#undef STAGE_W
  int col = lane & 15, rhi = lane >> 4;
#pragma unroll
  for (int q = 0; q < 4; ++q) {
    int n = nt * 128 + wc + q * 16 + col;
#pragma unroll
    for (int f = 0; f < 4; ++f)
#pragma unroll
      for (int r = 0; r < 4; ++r) {
        int m = mt * 128 + wr + f * 16 + rhi * 4 + r;
        encW[(size_t)m * 2048 + n] = f2b(acc[f][q][r]);
      }
  }
}

// ---- k_as: blocks 0-63 = per-b att2(broadcast MFMA)+scores+softmax; 64-191 = gates_he ----
__global__ __launch_bounds__(256) void k_as(int t, const unsigned short* __restrict__ hx,
                      const unsigned short* __restrict__ B1, const unsigned short* __restrict__ att1b,
                      const float* __restrict__ bd, const float* __restrict__ bih, const float* __restrict__ bhh,
                      const float* __restrict__ wf, const float* __restrict__ bfp,
                      const int* __restrict__ meta,
                      float* __restrict__ geh, float* __restrict__ out, float* __restrict__ alp){
  int bid = blockIdx.x;
  int tid = threadIdx.x, lane = tid & 63, w = tid >> 6;
  int rr = lane & 15, kb8 = (lane >> 4) * 8;
  if (bid >= 64) {
    // ---- gates_he wave GEMM (verbatim step1lite else-branch) ----
    int omega = 32 + (bid - 64);
    const unsigned short* pb = B1 + (size_t)(512 + (omega - 32) * 16 + rr) * 1024 + kb8;
    const unsigned short* pa0 = hx + (size_t)rr * 1024 + kb8;
    f32x4 acc[4];
#pragma unroll
    for (int f = 0; f < 4; ++f) acc[f] = (f32x4){0.f,0.f,0.f,0.f};
#pragma unroll 4
    for (int kk = 0; kk < 32; ++kk) {
      short8 bfr = *(const short8*)(pb + kk * 32);
#pragma unroll
      for (int f = 0; f < 4; ++f) {
        short8 afr = *(const short8*)(pa0 + (size_t)f * 16384 + kk * 32);
        acc[f] = __builtin_amdgcn_mfma_f32_16x16x32_bf16(afr, bfr, acc[f], 0, 0, 0);
      }
    }
    int col = lane & 15, rhi = lane >> 4;
    int j = (omega - 32) * 16 + col; int g = (j & 3) * 512 + (j >> 2);
    float bv = bih[g] + bhh[g];
#pragma unroll
    for (int f = 0; f < 4; ++f)
#pragma unroll
      for (int r = 0; r < 4; ++r) { int b = f * 16 + rhi * 4 + r; geh[(size_t)b * 2048 + j] = acc[f][r] + bv; }
    return;
  }
  // ---- per-b: att2 + scores + softmax ----
  int b = bid;
  if (b >= meta[128 + t]) return;
  __shared__ float a2s[512];
  __shared__ float sal[200];
  __shared__ float red[256];
  {
    const unsigned short* pa = hx + (size_t)b * 1024 + kb8;
    f32x4 acc[8];
#pragma unroll
    for (int q = 0; q < 8; ++q) acc[q] = (f32x4){0.f,0.f,0.f,0.f};
#pragma unroll 4
    for (int kk = 0; kk < 16; ++kk) {
      short8 afr = *(const short8*)(pa + kk * 32);
#pragma unroll
      for (int q = 0; q < 8; ++q) {
        const unsigned short* pb = B1 + (size_t)(w * 128 + q * 16 + rr) * 1024 + kb8;
        short8 bfr = *(const short8*)(pb + kk * 32);
        acc[q] = __builtin_amdgcn_mfma_f32_16x16x32_bf16(afr, bfr, acc[q], 0, 0, 0);
      }
    }
    if (lane < 16) {
#pragma unroll
      for (int q = 0; q < 8; ++q) {
        int n = w * 128 + q * 16 + lane;
        a2s[n] = acc[q][0] + bd[n];
      }
    }
  }
  __syncthreads();
  {
    float wfr[8], a2[8];
#pragma unroll
    for (int j = 0; j < 8; ++j) { wfr[j] = wf[lane * 8 + j]; a2[j] = a2s[lane * 8 + j]; }
    float bf0 = bfp[0];
    for (int i = 0; i < 49; ++i) {
      int p = i * 4 + w;
      short8 av = *(const short8*)(att1b + ((size_t)(b * 196 + p)) * 512 + lane * 8);
      float s = 0.f;
#pragma unroll
      for (int j = 0; j < 8; ++j) s += tanhf_fast(b2f((unsigned short)av[j]) + a2[j]) * wfr[j];
#pragma unroll
      for (int off = 32; off; off >>= 1) s += __shfl_xor(s, off);
      if (lane == 0) sal[p] = s + bf0;
    }
  }
  __syncthreads();
  {
    float v = (tid < 196) ? sal[tid] : -3.0e38f;
    red[tid] = v; __syncthreads();
    for (int s = 128; s; s >>= 1) { if (tid < s) red[tid] = fmaxf(red[tid], red[tid + s]); __syncthreads(); }
    float mx = red[0]; __syncthreads();
    float ex = (tid < 196) ? __expf(v - mx) : 0.f;
    red[tid] = ex; __syncthreads();
    for (int s = 128; s; s >>= 1) { if (tid < s) red[tid] += red[tid + s]; __syncthreads(); }
    float inv = 1.0f / red[0];
    if (tid < 196) {
      float al = ex * inv;
      alp[(size_t)b * 196 + tid] = al;
      out[PRED_ELEMS + ((size_t)b * 30 + t) * 196 + tid] = al;
    }
  }
}

// ---- k_gc: gates_ctx = alpha@encW + geh + cell + hh + emb (alpha precomputed) ----
__global__ __launch_bounds__(256) void k_gc(int t, const float* __restrict__ alp,
                      const unsigned short* __restrict__ encW, const float* __restrict__ geh,
                      const float* __restrict__ Wemb, const int* __restrict__ meta,
                      float* __restrict__ cbuf, unsigned short* __restrict__ hx,
                      unsigned short* __restrict__ hh){
  int b = blockIdx.y, ch = blockIdx.x;
  int tid = threadIdx.x, lane = tid & 63, w = tid >> 6;
  int na = meta[128 + t];
  __shared__ float sal[200];
  __shared__ float part[4][512];
  __shared__ float gt[512];

  if (b < na) {
    if (tid < 196) sal[tid] = alp[(size_t)b * 196 + tid];
    __syncthreads();
    const unsigned short* ep = encW + ((size_t)b * 196) * 2048 + ch * 512 + lane * 8;
    float s8[8];
#pragma unroll
    for (int j = 0; j < 8; ++j) s8[j] = 0.f;
#pragma unroll 7
    for (int i = 0; i < 49; ++i) {
      int p = w + i * 4;
      short8 vv = *(const short8*)(ep + (size_t)p * 2048);
      float a = sal[p];
#pragma unroll
      for (int j = 0; j < 8; ++j) s8[j] += a * b2f((unsigned short)vv[j]);
    }
#pragma unroll
    for (int j = 0; j < 8; ++j) part[w][lane * 8 + j] = s8[j];
    __syncthreads();
    int j0 = tid * 2;
    gt[j0]     = part[0][j0] + part[1][j0] + part[2][j0] + part[3][j0]
               + geh[(size_t)b * 2048 + ch * 512 + j0];
    gt[j0 + 1] = part[0][j0 + 1] + part[1][j0 + 1] + part[2][j0 + 1] + part[3][j0 + 1]
               + geh[(size_t)b * 2048 + ch * 512 + j0 + 1];
    __syncthreads();

    if (tid < 128) {
      int d = ch * 128 + tid;
      float ig = gt[tid * 4 + 0];
      float fg = gt[tid * 4 + 1];
      float gg = gt[tid * 4 + 2];
      float og = gt[tid * 4 + 3];
      float c0 = cbuf[(size_t)b * 512 + d];
      float ct = sigm(fg) * c0 + sigm(ig) * tanhf_fast(gg);
      float ht = sigm(og) * tanhf_fast(ct);
      cbuf[(size_t)b * 512 + d] = ct;
      unsigned short hb = f2b(ht);
      hx[(size_t)b * 1024 + d] = hb;
      hh[((size_t)t * 64 + b) * 512 + d] = hb;
      int cap = meta[160 + b * 31 + t + 1];
      hx[(size_t)b * 1024 + 512 + d] = f2b(Wemb[(size_t)cap * 512 + d]);
    }
  } else {
    if (tid < 128) {
      int d = ch * 128 + tid;
      unsigned short hold = hx[(size_t)b * 1024 + d];
      hh[((size_t)t * 64 + b) * 512 + d] = hold;
      int cap = meta[160 + b * 31 + t + 1];
      hx[(size_t)b * 1024 + 512 + d] = f2b(Wemb[(size_t)cap * 512 + d]);
    }
  }
}

// ---- pred: all-steps batched GEMM hh[1920x512] @ Wfcb^T -> out (masked) ----
__global__ __launch_bounds__(256) void k_pred(const unsigned short* __restrict__ hh,
                      const unsigned short* __restrict__ Wfcb, const float* __restrict__ bfc,
                      const int* __restrict__ meta, float* __restrict__ out){
  __shared__ __align__(16) unsigned short As[2][4096], Bs[2][4096];
  int tid = threadIdx.x, lane = tid & 63, w = tid >> 6;
  int mt = blockIdx.x % 15, nt = blockIdx.x / 15;   // 15 x 79
  int wr = (w >> 1) * 64, wc = (w & 1) * 64;
  int rr = lane & 15, kb = lane >> 4;
  f32x4 acc[4][4];
#pragma unroll
  for (int f = 0; f < 4; ++f)
#pragma unroll
    for (int q = 0; q < 4; ++q) acc[f][q] = (f32x4){0.f,0.f,0.f,0.f};

  const unsigned short* gA = hh + (size_t)mt * 128 * 512;
  int L0 = tid, L1 = tid + 256;
  size_t sa0 = (size_t)(L0 & 127) * 512 + ((L0 >> 7) << 3);
  size_t sa1 = (size_t)(L1 & 127) * 512 + ((L1 >> 7) << 3);
  int br0 = nt * 128 + (L0 & 127); if (br0 > 10015) br0 = 10015;
  int br1 = nt * 128 + (L1 & 127); if (br1 > 10015) br1 = 10015;
  size_t sb0 = (size_t)br0 * 512 + ((L0 >> 7) << 3);
  size_t sb1 = (size_t)br1 * 512 + ((L1 >> 7) << 3);
  int d0 = (w * 64) * 8, d1 = (w * 64 + 256) * 8;

#define STAGE_P(kk, bf) do { \
    gload16(gA + sa0 + (size_t)(kk) * 32, &As[bf][d0]); \
    gload16(Wfcb + sb0 + (size_t)(kk) * 32, &Bs[bf][d0]); \
    gload16(gA + sa1 + (size_t)(kk) * 32, &As[bf][d1]); \
    gload16(Wfcb + sb1 + (size_t)(kk) * 32, &Bs[bf][d1]); \
  } while (0)

  STAGE_P(0, 0);
  __syncthreads();
  for (int kk = 0; kk < 16; ++kk) {
    int cur = kk & 1;
    if (kk < 15) STAGE_P(kk + 1, cur ^ 1);
    short8 af[4], bq[4];
#pragma unroll
    for (int f = 0; f < 4; ++f)
      af[f] = *(const short8*)&As[cur][((kb << 7) + wr + f * 16 + rr) * 8];
#pragma unroll
    for (int q = 0; q < 4; ++q)
      bq[q] = *(const short8*)&Bs[cur][((kb << 7) + wc + q * 16 + rr) * 8];
#pragma unroll
    for (int f = 0; f < 4; ++f)
#pragma unroll
      for (int q = 0; q < 4; ++q)
        acc[f][q] = __builtin_amdgcn_mfma_f32_16x16x32_bf16(af[f], bq[q], acc[f][q], 0, 0, 0);
    __syncthreads();
  }
#undef STAGE_P
  int col = lane & 15, rhi = lane >> 4;
  int tt = mt * 2 + (wr >> 6);
  int na = meta[128 + tt];
#pragma unroll
  for (int q = 0; q < 4; ++q) {
    int n = nt * 128 + wc + q * 16 + col;
    if (n >= 10000) continue;
    float bv = bfc[n];
#pragma unroll
    for (int f = 0; f < 4; ++f)
#pragma unroll
      for (int r = 0; r < 4; ++r) {
        int b = f * 16 + rhi * 4 + r;
        if (b < na) out[(size_t)b * 300000 + (size_t)tt * 10000 + n] = acc[f][q][r] + bv;
      }
  }
}

extern "C" void kernel_launch(void* const* d_in, const int* in_sizes, int n_in,
                              void* d_out, int out_size, void* d_ws, size_t ws_size,
                              hipStream_t stream) {
  (void)in_sizes; (void)n_in; (void)ws_size;
  const float* enc  = (const float*)d_in[0];
  const int*   caps = (const int*)d_in[1];
  const int*   lens = (const int*)d_in[2];
  const float* Wemb = (const float*)d_in[3];
  const float* We   = (const float*)d_in[4];
  const float* be   = (const float*)d_in[5];
  const float* Wd   = (const float*)d_in[6];
  const float* bd   = (const float*)d_in[7];
  const float* wf   = (const float*)d_in[8];
  const float* bf   = (const float*)d_in[9];
  const float* Wih  = (const float*)d_in[10];
  const float* bih  = (const float*)d_in[11];
  const float* Whh  = (const float*)d_in[12];
  const float* bhh  = (const float*)d_in[13];
  const float* Wfc  = (const float*)d_in[14];
  const float* bfc  = (const float*)d_in[15];
  const float* Wh0  = (const float*)d_in[16];
  const float* bh0  = (const float*)d_in[17];
  const float* Wc0  = (const float*)d_in[18];
  const float* bc0  = (const float*)d_in[19];

  char* ws = (char*)d_ws;
  unsigned short* encb  = (unsigned short*)(ws + OFF_ENC);
  unsigned short* att1b = (unsigned short*)(ws + OFF_ATT1);
  unsigned short* B1    = (unsigned short*)(ws + OFF_B1);
  unsigned short* Wfcb  = (unsigned short*)(ws + OFF_WFC);
  unsigned short* Web   = (unsigned short*)(ws + OFF_WEB);
  unsigned short* B0    = (unsigned short*)(ws + OFF_B0);
  unsigned short* hh    = (unsigned short*)(ws + OFF_HH);
  unsigned short* B2    = (unsigned short*)(ws + OFF_B2);
  unsigned short* hx    = (unsigned short*)(ws + OFF_HX);
  float*          cbuf  = (float*)(ws + OFF_C);
  float*          geh   = (float*)(ws + OFF_GEH);
  float*          sc    = (float*)(ws + OFF_SC);
  unsigned short* ctxb  = (unsigned short*)(ws + OFF_CTX);
  int*            meta  = (int*)(ws + OFF_META);
  unsigned short* encWb = (unsigned short*)(ws + OFF_ENCW);
  unsigned short* meanb = ctxb;   // setup-time only
  float* out = (float*)d_out;

  hipMemsetAsync(d_out, 0, (size_t)out_size * sizeof(float), stream);
  k_meta<<<1, 64, 0, stream>>>(caps, lens, meta);
  k_encg<<<12544, 256, 0, stream>>>(enc, meta, encb);
  k_wconv<<<16160, 256, 0, stream>>>(We, Wh0, Wc0, Wd, Whh, Wih, Wfc, Web, B0, B1, Wfcb, B2);
  k_mean<<<dim3(4, 64), 256, 0, stream>>>(encb, meanb);
  k_h0c0<<<16, 256, 0, stream>>>(meanb, B0, bh0, bc0, hx, cbuf);
  k_emb0<<<64, 256, 0, stream>>>(Wemb, meta, hx);
  k_att1<<<392, 256, 0, stream>>>(encb, Web, be, att1b);
  k_encw<<<1664, 256, 0, stream>>>(encb, B2, encWb);

  for (int t = 0; t < 30; ++t) {
    k_as<<<192, 256, 0, stream>>>(t, hx, B1, att1b, bd, bih, bhh, wf, bf, meta, geh, out, sc);
    k_gc<<<dim3(4, 64), 256, 0, stream>>>(t, sc, encWb, geh, Wemb, meta, cbuf, hx, hh);
  }
  k_pred<<<1185, 256, 0, stream>>>(hh, Wfcb, bfc, meta, out);
}

// Round 13
// 2116.643 us; speedup vs baseline: 1.2860x; 1.2860x over previous
//
#include <hip/hip_runtime.h>
#include <cstdint>
#include <cstddef>

typedef __attribute__((ext_vector_type(8))) short short8;
typedef __attribute__((ext_vector_type(4))) float f32x4;

#define DEV static __device__ __forceinline__

#define PRED_ELEMS 19200000ULL   // 64*30*10000

// ---- workspace layout (bytes) ----
#define OFF_ENC   0ULL          // ushort [12544][2048] sorted enc bf16
#define OFF_ATT1  51380224ULL   // ushort [12544][512]
#define OFF_B1    64225280ULL   // ushort [2560][1024]  [Wd|0 ; Whh|Wih_e interleaved]
#define OFF_WFC   69468160ULL   // ushort [10016][512]  Wfc bf16, zero padded
#define OFF_WEB   79724544ULL   // ushort [512][2048]   We bf16
#define OFF_B0    81821696ULL   // ushort [1024][2048]  [Wh0;Wc0] (dead after k_h0c0)
#define OFF_HH    81821696ULL   // ushort [30][64][512] h history (reuses B0; 1.97MB)
#define OFF_PA2   83787776ULL   // float  [4][64][512]  partial att2 (512KB, in dead B0 gap)
#define OFF_B2    86016000ULL   // ushort [2048][2048]  Wih ctx-part, interleaved rows
#define OFF_HX    94404608ULL   // ushort [64][1024]    [h | e_t] bf16
#define OFF_C     94535680ULL   // float  [64][512]
#define OFF_GEH   94797824ULL   // float  [64][2048]    gates from h,e (interleaved 4d+q)
#define OFF_SC    95322112ULL   // float  [64][196]     alpha
#define OFF_CTX   95372288ULL   // ushort [64][2048]    (meanb during setup)
#define OFF_META  95634432ULL   // int: idx[64] dec[64] nact[32] caps[64*31]
#define OFF_ENCW  96000000ULL   // ushort [12544][2048] enc @ Wih_ctx^T (j-interleaved)

DEV float b2f(unsigned short u){ unsigned v = ((unsigned)u) << 16; float f; __builtin_memcpy(&f, &v, 4); return f; }
DEV unsigned short f2b(float x){ unsigned v; __builtin_memcpy(&v, &x, 4); unsigned r = v + 0x7fffu + ((v >> 16) & 1u); return (unsigned short)(r >> 16); }
DEV float sigm(float x){ return 1.0f / (1.0f + __expf(-x)); }
DEV float tanhf_fast(float x){ float e = __expf(2.0f * x); return 1.0f - 2.0f / (e + 1.0f); }

DEV void gload16(const void* g, void* l){
  __builtin_amdgcn_global_load_lds((const __attribute__((address_space(1))) unsigned int*)g,
                                   (__attribute__((address_space(3))) unsigned int*)l, 16, 0, 0);
}

// ---- LDS-staged 64x64 core (used only by one-time k_h0c0) ----
DEV void mm_core(const unsigned short* A, int ldA, int m0,
                 const unsigned short* Bm, int ldB, int n0,
                 int kIters, unsigned short* As, unsigned short* Bs, f32x4 acc[4])
{
  const int tid = threadIdx.x;
  const int lane = tid & 63, w = tid >> 6;
  const unsigned short* ga = A + (size_t)(m0 + lane) * ldA + w * 8;
  const unsigned short* gb = Bm + (size_t)(n0 + lane) * ldB + w * 8;
  unsigned short* la = As + w * 512;
  unsigned short* lb = Bs + w * 512;
  const int kb = lane >> 4, rr = lane & 15;
  for (int kk = 0; kk < kIters; ++kk) {
    gload16(ga, la); gload16(gb, lb);
    ga += 32; gb += 32;
    asm volatile("s_waitcnt vmcnt(0)" ::: "memory");
    __syncthreads();
    short8 bfr = *(const short8*)(Bs + (size_t)(kb * 64 + w * 16 + rr) * 8);
#pragma unroll
    for (int f = 0; f < 4; ++f) {
      short8 afr = *(const short8*)(As + (size_t)(kb * 64 + f * 16 + rr) * 8);
      acc[f] = __builtin_amdgcn_mfma_f32_16x16x32_bf16(afr, bfr, acc[f], 0, 0, 0);
    }
    __syncthreads();
  }
}

__global__ void k_meta(const int* __restrict__ caps, const int* __restrict__ lens, int* __restrict__ meta){
  int j = threadIdx.x;
  int lj = lens[j];
  int rank = 0;
  for (int k = 0; k < 64; ++k) { int lk = lens[k]; rank += (lk > lj) || (lk == lj && k < j); }
  meta[rank] = j; meta[64 + rank] = lj - 1;
  for (int t = 0; t < 31; ++t) meta[160 + rank * 31 + t] = caps[j * 31 + t];
  __syncthreads();
  if (j < 30) { int c = 0; for (int b = 0; b < 64; ++b) c += (meta[64 + b] > j); meta[128 + j] = c; }
}

__global__ __launch_bounds__(256) void k_encg(const float* __restrict__ enc, const int* __restrict__ meta, unsigned short* __restrict__ encb){
  int row = blockIdx.x; int b = row / 196, p = row % 196;
  const float* src = enc + ((size_t)meta[b] * 196 + p) * 2048;
  unsigned short* dst = encb + (size_t)row * 2048;
  int e0 = threadIdx.x * 8;
  short8 o;
#pragma unroll
  for (int j = 0; j < 8; ++j) o[j] = (short)f2b(src[e0 + j]);
  *(short8*)(dst + e0) = o;
}

__global__ __launch_bounds__(256) void k_wconv(const float* We, const float* Wh0, const float* Wc0,
                        const float* Wd, const float* Whh, const float* Wih, const float* Wfc,
                        unsigned short* Web, unsigned short* B0, unsigned short* B1,
                        unsigned short* Wfcb, unsigned short* B2){
  int bid = blockIdx.x, tid = threadIdx.x;
  if (bid < 512) {
    const float* s = We + (size_t)bid * 2048; unsigned short* d = Web + (size_t)bid * 2048;
    int e0 = tid * 8; short8 o;
#pragma unroll
    for (int j = 0; j < 8; ++j) o[j] = (short)f2b(s[e0 + j]);
    *(short8*)(d + e0) = o;
  } else if (bid < 1536) {
    int r = bid - 512;
    const float* s = (r < 512) ? (Wh0 + (size_t)r * 2048) : (Wc0 + (size_t)(r - 512) * 2048);
    unsigned short* d = B0 + (size_t)r * 2048;
    int e0 = tid * 8; short8 o;
#pragma unroll
    for (int j = 0; j < 8; ++j) o[j] = (short)f2b(s[e0 + j]);
    *(short8*)(d + e0) = o;
  } else if (bid < 3584) {   // B2: 2048 rows, j-interleaved (g = (j&3)*512 + (j>>2))
    int jr = bid - 1536; int g = (jr & 3) * 512 + (jr >> 2);
    const float* s = Wih + (size_t)g * 2560 + 512;
    unsigned short* d = B2 + (size_t)jr * 2048;
    int e0 = tid * 8; short8 o;
#pragma unroll
    for (int j = 0; j < 8; ++j) o[j] = (short)f2b(s[e0 + j]);
    *(short8*)(d + e0) = o;
  } else if (bid < 6144) {   // B1: 2560 rows
    int n = bid - 3584; unsigned short* d = B1 + (size_t)n * 1024;
    int k0 = tid * 4;
    if (n < 512) {
#pragma unroll
      for (int j = 0; j < 4; ++j) { int k = k0 + j; d[k] = (k < 512) ? f2b(Wd[(size_t)n * 512 + k]) : (unsigned short)0; }
    } else {
      int j2 = n - 512; int g = (j2 & 3) * 512 + (j2 >> 2);
#pragma unroll
      for (int j = 0; j < 4; ++j) { int k = k0 + j;
        d[k] = (k < 512) ? f2b(Whh[(size_t)g * 512 + k]) : f2b(Wih[(size_t)g * 2560 + (k - 512)]); }
    }
  } else {                   // Wfcb: 10016 rows
    int v = bid - 6144; unsigned short* d = Wfcb + (size_t)v * 512;
    int k0 = tid * 2;
#pragma unroll
    for (int j = 0; j < 2; ++j) d[k0 + j] = (v < 10000) ? f2b(Wfc[(size_t)v * 512 + k0 + j]) : (unsigned short)0;
  }
}

__global__ __launch_bounds__(256) void k_mean(const unsigned short* __restrict__ encb, unsigned short* __restrict__ meanb){
  int b = blockIdx.y, ch = blockIdx.x;
  int e = ch * 512 + threadIdx.x * 2;
  const unsigned short* ep = encb + (size_t)b * 196 * 2048 + e;
  float s0 = 0.f, s1 = 0.f;
  for (int p = 0; p < 196; ++p) {
    unsigned u = *(const unsigned*)(ep + (size_t)p * 2048);
    s0 += b2f((unsigned short)(u & 0xffff));
    s1 += b2f((unsigned short)(u >> 16));
  }
  const float inv = 1.0f / 196.0f;
  unsigned o = ((unsigned)f2b(s1 * inv) << 16) | f2b(s0 * inv);
  *(unsigned*)(meanb + (size_t)b * 2048 + e) = o;
}

__global__ __launch_bounds__(256) void k_h0c0(const unsigned short* meanb, const unsigned short* B0,
                      const float* bh0, const float* bc0, unsigned short* hx, float* cbuf){
  __shared__ __align__(16) unsigned short As[2048], Bs[2048];
  f32x4 acc[4];
#pragma unroll
  for (int f = 0; f < 4; ++f) acc[f] = (f32x4){0.f,0.f,0.f,0.f};
  int nt = blockIdx.x;
  mm_core(meanb, 2048, 0, B0, 2048, nt * 64, 64, As, Bs, acc);
  int lane = threadIdx.x & 63, w = threadIdx.x >> 6;
  int col = lane & 15, rhi = lane >> 4;
  int n = nt * 64 + w * 16 + col;
#pragma unroll
  for (int f = 0; f < 4; ++f)
#pragma unroll
    for (int r = 0; r < 4; ++r) {
      int b = f * 16 + rhi * 4 + r; float v = acc[f][r];
      if (n < 512) hx[(size_t)b * 1024 + n] = f2b(v + bh0[n]);
      else cbuf[(size_t)b * 512 + (n - 512)] = v + bc0[n - 512];
    }
}

__global__ void k_emb0(const float* __restrict__ Wemb, const int* __restrict__ meta, unsigned short* __restrict__ hx){
  int b = blockIdx.x;
  int cap = meta[160 + b * 31];
  for (int j = threadIdx.x; j < 512; j += 256)
    hx[(size_t)b * 1024 + 512 + j] = f2b(Wemb[(size_t)cap * 512 + j]);
}

// ---- att1: 128x128 tile GEMM with XCD-grouped block swizzle ----
__global__ __launch_bounds__(256) void k_att1(const unsigned short* __restrict__ encb,
                      const unsigned short* __restrict__ Web,
                      const float* __restrict__ be, unsigned short* __restrict__ att1b){
  __shared__ __align__(16) unsigned short As[2][4096], Bs[2][4096];
  int tid = threadIdx.x, lane = tid & 63, w = tid >> 6;
  int bid = blockIdx.x, mt, nt;
  if (bid < 384) { mt = (bid >> 5) * 8 + (bid & 7); nt = (bid >> 3) & 3; }
  else           { mt = 96 + ((bid - 384) >> 2);    nt = (bid - 384) & 3; }
  int wr = (w >> 1) * 64, wc = (w & 1) * 64;
  int rr = lane & 15, kb = lane >> 4;
  f32x4 acc[4][4];
#pragma unroll
  for (int f = 0; f < 4; ++f)
#pragma unroll
    for (int q = 0; q < 4; ++q) acc[f][q] = (f32x4){0.f,0.f,0.f,0.f};

  const unsigned short* gA = encb + (size_t)mt * 128 * 2048;
  const unsigned short* gB = Web + (size_t)nt * 128 * 2048;
  int L0 = tid, L1 = tid + 256;
  size_t s0 = (size_t)(L0 & 127) * 2048 + ((L0 >> 7) << 3);
  size_t s1 = (size_t)(L1 & 127) * 2048 + ((L1 >> 7) << 3);
  int d0 = (w * 64) * 8, d1 = (w * 64 + 256) * 8;

#define STAGE_A1(kk, bf) do { \
    gload16(gA + s0 + (size_t)(kk) * 32, &As[bf][d0]); \
    gload16(gB + s0 + (size_t)(kk) * 32, &Bs[bf][d0]); \
    gload16(gA + s1 + (size_t)(kk) * 32, &As[bf][d1]); \
    gload16(gB + s1 + (size_t)(kk) * 32, &Bs[bf][d1]); \
  } while (0)

  STAGE_A1(0, 0);
  __syncthreads();
  for (int kk = 0; kk < 64; ++kk) {
    int cur = kk & 1;
    if (kk < 63) STAGE_A1(kk + 1, cur ^ 1);
    short8 af[4], bq[4];
#pragma unroll
    for (int f = 0; f < 4; ++f)
      af[f] = *(const short8*)&As[cur][((kb << 7) + wr + f * 16 + rr) * 8];
#pragma unroll
    for (int q = 0; q < 4; ++q)
      bq[q] = *(const short8*)&Bs[cur][((kb << 7) + wc + q * 16 + rr) * 8];
#pragma unroll
    for (int f = 0; f < 4; ++f)
#pragma unroll
      for (int q = 0; q < 4; ++q)
        acc[f][q] = __builtin_amdgcn_mfma_f32_16x16x32_bf16(af[f], bq[q], acc[f][q], 0, 0, 0);
    __syncthreads();
  }
#undef STAGE_A1
  int col = lane & 15, rhi = lane >> 4;
#pragma unroll
  for (int q = 0; q < 4; ++q) {
    int n = nt * 128 + wc + q * 16 + col;
    float bev = be[n];
#pragma unroll
    for (int f = 0; f < 4; ++f)
#pragma unroll
      for (int r = 0; r < 4; ++r) {
        int m = mt * 128 + wr + f * 16 + rhi * 4 + r;
        att1b[(size_t)m * 512 + n] = f2b(acc[f][q][r] + bev);
      }
  }
}

// ---- encW = enc @ B2^T (one-time): XCD-grouped swizzle ----
__global__ __launch_bounds__(256) void k_encw(const unsigned short* __restrict__ encb,
                      const unsigned short* __restrict__ B2, unsigned short* __restrict__ encW){
  __shared__ __align__(16) unsigned short As[2][4096], Bs[2][4096];
  int tid = threadIdx.x, lane = tid & 63, w = tid >> 6;
  int xcd = blockIdx.x & 7, slot = blockIdx.x >> 3;
  int mtl = slot >> 4, nt = slot & 15;
  int mt = mtl * 8 + xcd;
  if (mt >= 98) return;
  int wr = (w >> 1) * 64, wc = (w & 1) * 64;
  int rr = lane & 15, kb = lane >> 4;
  f32x4 acc[4][4];
#pragma unroll
  for (int f = 0; f < 4; ++f)
#pragma unroll
    for (int q = 0; q < 4; ++q) acc[f][q] = (f32x4){0.f,0.f,0.f,0.f};

  const unsigned short* gA = encb + (size_t)mt * 128 * 2048;
  const unsigned short* gB = B2 + (size_t)nt * 128 * 2048;
  int L0 = tid, L1 = tid + 256;
  size_t s0 = (size_t)(L0 & 127) * 2048 + ((L0 >> 7) << 3);
  size_t s1 = (size_t)(L1 & 127) * 2048 + ((L1 >> 7) << 3);
  int d0 = (w * 64) * 8, d1 = (w * 64 + 256) * 8;

#define STAGE_W(kk, bf) do { \
    gload16(gA + s0 + (size_t)(kk) * 32, &As[bf][d0]); \
    gload16(gB + s0 + (size_t)(kk) * 32, &Bs[bf][d0]); \
    gload16(gA + s1 + (size_t)(kk) * 32, &As[bf][d1]); \
    gload16(gB + s1 + (size_t)(kk) * 32, &Bs[bf][d1]); \
  } while (0)

  STAGE_W(0, 0);
  __syncthreads();
  for (int kk = 0; kk < 64; ++kk) {
    int cur = kk & 1;
    if (kk < 63) STAGE_W(kk + 1, cur ^ 1);
    short8 af[4], bq[4];
#pragma unroll
    for (int f = 0; f < 4; ++f)
      af[f] = *(const short8*)&As[cur][((kb << 7) + wr + f * 16 + rr) * 8];
#pragma unroll
    for (int q = 0; q < 4; ++q)
      bq[q] = *(const short8*)&Bs[cur][((kb << 7) + wc + q * 16 + rr) * 8];
#pragma unroll
    for (int f = 0; f < 4; ++f)
#pragma unroll
      for (int q = 0; q < 4; ++q)
        acc[f][q] = __builtin_amdgcn_mfma_f32_16x16x32_bf16(af[f], bq[q], acc[f][q], 0, 0, 0);
    __syncthreads();
  }
#undef STAGE_W
  int col = lane & 15, rhi = lane >> 4;
#pragma unroll
  for (int q = 0; q < 4; ++q) {
    int n = nt * 128 + wc + q * 16 + col;
#pragma unroll
    for (int f = 0; f < 4; ++f)
#pragma unroll
      for (int r = 0; r < 4; ++r) {
        int m = mt * 128 + wr + f * 16 + rhi * 4 + r;
        encW[(size_t)m * 2048 + n] = f2b(acc[f][q][r]);
      }
  }
}

// ---- k_att2i (init only): pa2[0] = h0 @ Wd^T (no bias), 8 blocks x 4 waves ----
__global__ __launch_bounds__(256) void k_att2i(const unsigned short* __restrict__ hx,
                      const unsigned short* __restrict__ B1, float* __restrict__ pa2){
  int w = threadIdx.x >> 6, lane = threadIdx.x & 63;
  int omega = blockIdx.x * 4 + w;   // 0..31
  int rr = lane & 15, kb8 = (lane >> 4) * 8;
  const unsigned short* pb = B1 + (size_t)(omega * 16 + rr) * 1024 + kb8;
  const unsigned short* pa0 = hx + (size_t)rr * 1024 + kb8;
  f32x4 acc[4];
#pragma unroll
  for (int f = 0; f < 4; ++f) acc[f] = (f32x4){0.f,0.f,0.f,0.f};
#pragma unroll 4
  for (int kk = 0; kk < 16; ++kk) {
    short8 bfr = *(const short8*)(pb + kk * 32);
#pragma unroll
    for (int f = 0; f < 4; ++f) {
      short8 afr = *(const short8*)(pa0 + (size_t)f * 16384 + kk * 32);
      acc[f] = __builtin_amdgcn_mfma_f32_16x16x32_bf16(afr, bfr, acc[f], 0, 0, 0);
    }
  }
  int col = lane & 15, rhi = lane >> 4;
  int n = omega * 16 + col;
#pragma unroll
  for (int f = 0; f < 4; ++f)
#pragma unroll
    for (int r = 0; r < 4; ++r) { int b = f * 16 + rhi * 4 + r; pa2[(size_t)b * 512 + n] = acc[f][r]; }
}

// ---- k_scg: blocks 0-63 = per-b [sum pa2 -> a2s] + all-196 scores + softmax + alpha;
//             blocks 64-191 = gates_he wave-GEMM ----
__global__ __launch_bounds__(256) void k_scg(int t, const unsigned short* __restrict__ hx,
                      const unsigned short* __restrict__ B1, const unsigned short* __restrict__ att1b,
                      const float* __restrict__ pa2,
                      const float* __restrict__ bd, const float* __restrict__ bih, const float* __restrict__ bhh,
                      const float* __restrict__ wf, const float* __restrict__ bfp,
                      const int* __restrict__ meta,
                      float* __restrict__ geh, float* __restrict__ out, float* __restrict__ alp){
  int bid = blockIdx.x;
  int tid = threadIdx.x, lane = tid & 63, w = tid >> 6;
  int rr = lane & 15, kb8 = (lane >> 4) * 8;
  if (bid >= 64) {
    // ---- gates_he wave GEMM (non-redundant; R12-verified branch) ----
    int jblk = bid - 64;
    const unsigned short* pb = B1 + (size_t)(512 + jblk * 16 + rr) * 1024 + kb8;
    const unsigned short* pa0 = hx + (size_t)rr * 1024 + kb8;
    f32x4 acc[4];
#pragma unroll
    for (int f = 0; f < 4; ++f) acc[f] = (f32x4){0.f,0.f,0.f,0.f};
#pragma unroll 4
    for (int kk = 0; kk < 32; ++kk) {
      short8 bfr = *(const short8*)(pb + kk * 32);
#pragma unroll
      for (int f = 0; f < 4; ++f) {
        short8 afr = *(const short8*)(pa0 + (size_t)f * 16384 + kk * 32);
        acc[f] = __builtin_amdgcn_mfma_f32_16x16x32_bf16(afr, bfr, acc[f], 0, 0, 0);
      }
    }
    int col = lane & 15, rhi = lane >> 4;
    int j = jblk * 16 + col; int g = (j & 3) * 512 + (j >> 2);
    float bv = bih[g] + bhh[g];
#pragma unroll
    for (int f = 0; f < 4; ++f)
#pragma unroll
      for (int r = 0; r < 4; ++r) { int b = f * 16 + rhi * 4 + r; geh[(size_t)b * 2048 + j] = acc[f][r] + bv; }
    return;
  }
  // ---- per-b: sum partial att2 + scores + softmax ----
  int b = bid;
  if (b >= meta[128 + t]) return;
  __shared__ float a2s[512];
  __shared__ float sal[200];
  __shared__ float red[256];
#pragma unroll
  for (int r = 0; r < 2; ++r) {
    int n = tid + r * 256;
    a2s[n] = pa2[(size_t)b * 512 + n] + pa2[(size_t)(64 + b) * 512 + n]
           + pa2[(size_t)(128 + b) * 512 + n] + pa2[(size_t)(192 + b) * 512 + n] + bd[n];
  }
  __syncthreads();
  {
    float wfr[8], a2[8];
#pragma unroll
    for (int j = 0; j < 8; ++j) { wfr[j] = wf[lane * 8 + j]; a2[j] = a2s[lane * 8 + j]; }
    float bf0 = bfp[0];
    for (int i = 0; i < 49; ++i) {
      int p = i * 4 + w;
      short8 av = *(const short8*)(att1b + ((size_t)(b * 196 + p)) * 512 + lane * 8);
      float s = 0.f;
#pragma unroll
      for (int j = 0; j < 8; ++j) s += tanhf_fast(b2f((unsigned short)av[j]) + a2[j]) * wfr[j];
#pragma unroll
      for (int off = 32; off; off >>= 1) s += __shfl_xor(s, off);
      if (lane == 0) sal[p] = s + bf0;
    }
  }
  __syncthreads();
  {
    float v = (tid < 196) ? sal[tid] : -3.0e38f;
    red[tid] = v; __syncthreads();
    for (int s = 128; s; s >>= 1) { if (tid < s) red[tid] = fmaxf(red[tid], red[tid + s]); __syncthreads(); }
    float mx = red[0]; __syncthreads();
    float ex = (tid < 196) ? __expf(v - mx) : 0.f;
    red[tid] = ex; __syncthreads();
    for (int s = 128; s; s >>= 1) { if (tid < s) red[tid] += red[tid + s]; __syncthreads(); }
    float inv = 1.0f / red[0];
    if (tid < 196) {
      float al = ex * inv;
      alp[(size_t)b * 196 + tid] = al;
      out[PRED_ELEMS + ((size_t)b * 30 + t) * 196 + tid] = al;
    }
  }
}

// ---- k_gc: gates_ctx = alpha@encW + geh + cell + hh + emb + partial-att2 push ----
__global__ __launch_bounds__(256) void k_gc(int t, const float* __restrict__ alp,
                      const unsigned short* __restrict__ encW, const float* __restrict__ geh,
                      const unsigned short* __restrict__ B1,
                      const float* __restrict__ Wemb, const int* __restrict__ meta,
                      float* __restrict__ cbuf, unsigned short* __restrict__ hx,
                      unsigned short* __restrict__ hh, float* __restrict__ pa2){
  int b = blockIdx.y, ch = blockIdx.x;
  int tid = threadIdx.x, lane = tid & 63, w = tid >> 6;
  int na = meta[128 + t];
  __shared__ float sal[200];
  __shared__ float part[4][512];
  __shared__ float gt[512];
  __shared__ float hs[128];

  if (b < na) {
    if (tid < 196) sal[tid] = alp[(size_t)b * 196 + tid];
    __syncthreads();
    const unsigned short* ep = encW + ((size_t)b * 196) * 2048 + ch * 512 + lane * 8;
    float s8[8];
#pragma unroll
    for (int j = 0; j < 8; ++j) s8[j] = 0.f;
#pragma unroll 7
    for (int i = 0; i < 49; ++i) {
      int p = w + i * 4;
      short8 vv = *(const short8*)(ep + (size_t)p * 2048);
      float a = sal[p];
#pragma unroll
      for (int j = 0; j < 8; ++j) s8[j] += a * b2f((unsigned short)vv[j]);
    }
#pragma unroll
    for (int j = 0; j < 8; ++j) part[w][lane * 8 + j] = s8[j];
    __syncthreads();
    int j0 = tid * 2;
    gt[j0]     = part[0][j0] + part[1][j0] + part[2][j0] + part[3][j0]
               + geh[(size_t)b * 2048 + ch * 512 + j0];
    gt[j0 + 1] = part[0][j0 + 1] + part[1][j0 + 1] + part[2][j0 + 1] + part[3][j0 + 1]
               + geh[(size_t)b * 2048 + ch * 512 + j0 + 1];
    __syncthreads();

    if (tid < 128) {
      int d = ch * 128 + tid;
      float ig = gt[tid * 4 + 0];
      float fg = gt[tid * 4 + 1];
      float gg = gt[tid * 4 + 2];
      float og = gt[tid * 4 + 3];
      float c0 = cbuf[(size_t)b * 512 + d];
      float ct = sigm(fg) * c0 + sigm(ig) * tanhf_fast(gg);
      float ht = sigm(og) * tanhf_fast(ct);
      cbuf[(size_t)b * 512 + d] = ct;
      unsigned short hb = f2b(ht);
      hs[tid] = b2f(hb);     // quantized h for consistency with GEMM path
      hx[(size_t)b * 1024 + d] = hb;
      hh[((size_t)t * 64 + b) * 512 + d] = hb;
      int cap = meta[160 + b * 31 + t + 1];
      hx[(size_t)b * 1024 + 512 + d] = f2b(Wemb[(size_t)cap * 512 + d]);
    }
  } else {
    if (tid < 128) {
      int d = ch * 128 + tid;
      unsigned short hold = hx[(size_t)b * 1024 + d];
      hs[tid] = b2f(hold);
      hh[((size_t)t * 64 + b) * 512 + d] = hold;
      int cap = meta[160 + b * 31 + t + 1];
      hx[(size_t)b * 1024 + 512 + d] = f2b(Wemb[(size_t)cap * 512 + d]);
    }
  }
  __syncthreads();
  // ---- partial att2 push for step t+1: pa2[ch][b][n] = sum_k hs[k] * Wd[n][ch*128+k] ----
#pragma unroll
  for (int r = 0; r < 2; ++r) {
    int n = tid + r * 256;
    const unsigned short* wp = B1 + (size_t)n * 1024 + ch * 128;
    float s = 0.f;
#pragma unroll
    for (int kk = 0; kk < 16; ++kk) {
      short8 wv = *(const short8*)(wp + kk * 8);
#pragma unroll
      for (int j = 0; j < 8; ++j) s += hs[kk * 8 + j] * b2f((unsigned short)wv[j]);
    }
    pa2[((size_t)ch * 64 + b) * 512 + n] = s;
  }
}

// ---- pred: all-steps batched GEMM hh[1920x512] @ Wfcb^T -> out (masked) ----
__global__ __launch_bounds__(256) void k_pred(const unsigned short* __restrict__ hh,
                      const unsigned short* __restrict__ Wfcb, const float* __restrict__ bfc,
                      const int* __restrict__ meta, float* __restrict__ out){
  __shared__ __align__(16) unsigned short As[2][4096], Bs[2][4096];
  int tid = threadIdx.x, lane = tid & 63, w = tid >> 6;
  int mt = blockIdx.x % 15, nt = blockIdx.x / 15;   // 15 x 79
  int wr = (w >> 1) * 64, wc = (w & 1) * 64;
  int rr = lane & 15, kb = lane >> 4;
  f32x4 acc[4][4];
#pragma unroll
  for (int f = 0; f < 4; ++f)
#pragma unroll
    for (int q = 0; q < 4; ++q) acc[f][q] = (f32x4){0.f,0.f,0.f,0.f};

  const unsigned short* gA = hh + (size_t)mt * 128 * 512;
  int L0 = tid, L1 = tid + 256;
  size_t sa0 = (size_t)(L0 & 127) * 512 + ((L0 >> 7) << 3);
  size_t sa1 = (size_t)(L1 & 127) * 512 + ((L1 >> 7) << 3);
  int br0 = nt * 128 + (L0 & 127); if (br0 > 10015) br0 = 10015;
  int br1 = nt * 128 + (L1 & 127); if (br1 > 10015) br1 = 10015;
  size_t sb0 = (size_t)br0 * 512 + ((L0 >> 7) << 3);
  size_t sb1 = (size_t)br1 * 512 + ((L1 >> 7) << 3);
  int d0 = (w * 64) * 8, d1 = (w * 64 + 256) * 8;

#define STAGE_P(kk, bf) do { \
    gload16(gA + sa0 + (size_t)(kk) * 32, &As[bf][d0]); \
    gload16(Wfcb + sb0 + (size_t)(kk) * 32, &Bs[bf][d0]); \
    gload16(gA + sa1 + (size_t)(kk) * 32, &As[bf][d1]); \
    gload16(Wfcb + sb1 + (size_t)(kk) * 32, &Bs[bf][d1]); \
  } while (0)

  STAGE_P(0, 0);
  __syncthreads();
  for (int kk = 0; kk < 16; ++kk) {
    int cur = kk & 1;
    if (kk < 15) STAGE_P(kk + 1, cur ^ 1);
    short8 af[4], bq[4];
#pragma unroll
    for (int f = 0; f < 4; ++f)
      af[f] = *(const short8*)&As[cur][((kb << 7) + wr + f * 16 + rr) * 8];
#pragma unroll
    for (int q = 0; q < 4; ++q)
      bq[q] = *(const short8*)&Bs[cur][((kb << 7) + wc + q * 16 + rr) * 8];
#pragma unroll
    for (int f = 0; f < 4; ++f)
#pragma unroll
      for (int q = 0; q < 4; ++q)
        acc[f][q] = __builtin_amdgcn_mfma_f32_16x16x32_bf16(af[f], bq[q], acc[f][q], 0, 0, 0);
    __syncthreads();
  }
#undef STAGE_P
  int col = lane & 15, rhi = lane >> 4;
  int tt = mt * 2 + (wr >> 6);
  int na = meta[128 + tt];
#pragma unroll
  for (int q = 0; q < 4; ++q) {
    int n = nt * 128 + wc + q * 16 + col;
    if (n >= 10000) continue;
    float bv = bfc[n];
#pragma unroll
    for (int f = 0; f < 4; ++f)
#pragma unroll
      for (int r = 0; r < 4; ++r) {
        int b = f * 16 + rhi * 4 + r;
        if (b < na) out[(size_t)b * 300000 + (size_t)tt * 10000 + n] = acc[f][q][r] + bv;
      }
  }
}

extern "C" void kernel_launch(void* const* d_in, const int* in_sizes, int n_in,
                              void* d_out, int out_size, void* d_ws, size_t ws_size,
                              hipStream_t stream) {
  (void)in_sizes; (void)n_in; (void)ws_size;
  const float* enc  = (const float*)d_in[0];
  const int*   caps = (const int*)d_in[1];
  const int*   lens = (const int*)d_in[2];
  const float* Wemb = (const float*)d_in[3];
  const float* We   = (const float*)d_in[4];
  const float* be   = (const float*)d_in[5];
  const float* Wd   = (const float*)d_in[6];
  const float* bd   = (const float*)d_in[7];
  const float* wf   = (const float*)d_in[8];
  const float* bf   = (const float*)d_in[9];
  const float* Wih  = (const float*)d_in[10];
  const float* bih  = (const float*)d_in[11];
  const float* Whh  = (const float*)d_in[12];
  const float* bhh  = (const float*)d_in[13];
  const float* Wfc  = (const float*)d_in[14];
  const float* bfc  = (const float*)d_in[15];
  const float* Wh0  = (const float*)d_in[16];
  const float* bh0  = (const float*)d_in[17];
  const float* Wc0  = (const float*)d_in[18];
  const float* bc0  = (const float*)d_in[19];

  char* ws = (char*)d_ws;
  unsigned short* encb  = (unsigned short*)(ws + OFF_ENC);
  unsigned short* att1b = (unsigned short*)(ws + OFF_ATT1);
  unsigned short* B1    = (unsigned short*)(ws + OFF_B1);
  unsigned short* Wfcb  = (unsigned short*)(ws + OFF_WFC);
  unsigned short* Web   = (unsigned short*)(ws + OFF_WEB);
  unsigned short* B0    = (unsigned short*)(ws + OFF_B0);
  unsigned short* hh    = (unsigned short*)(ws + OFF_HH);
  float*          pa2   = (float*)(ws + OFF_PA2);
  unsigned short* B2    = (unsigned short*)(ws + OFF_B2);
  unsigned short* hx    = (unsigned short*)(ws + OFF_HX);
  float*          cbuf  = (float*)(ws + OFF_C);
  float*          geh   = (float*)(ws + OFF_GEH);
  float*          sc    = (float*)(ws + OFF_SC);
  unsigned short* ctxb  = (unsigned short*)(ws + OFF_CTX);
  int*            meta  = (int*)(ws + OFF_META);
  unsigned short* encWb = (unsigned short*)(ws + OFF_ENCW);
  unsigned short* meanb = ctxb;   // setup-time only
  float* out = (float*)d_out;

  hipMemsetAsync(d_out, 0, (size_t)out_size * sizeof(float), stream);
  k_meta<<<1, 64, 0, stream>>>(caps, lens, meta);
  k_encg<<<12544, 256, 0, stream>>>(enc, meta, encb);
  k_wconv<<<16160, 256, 0, stream>>>(We, Wh0, Wc0, Wd, Whh, Wih, Wfc, Web, B0, B1, Wfcb, B2);
  k_mean<<<dim3(4, 64), 256, 0, stream>>>(encb, meanb);
  k_h0c0<<<16, 256, 0, stream>>>(meanb, B0, bh0, bc0, hx, cbuf);
  k_emb0<<<64, 256, 0, stream>>>(Wemb, meta, hx);
  // init pa2: slice 0 = full h0@Wd^T, slices 1..3 = 0
  hipMemsetAsync(pa2 + 64 * 512, 0, 3 * 64 * 512 * sizeof(float), stream);
  k_att2i<<<8, 256, 0, stream>>>(hx, B1, pa2);
  k_att1<<<392, 256, 0, stream>>>(encb, Web, be, att1b);
  k_encw<<<1664, 256, 0, stream>>>(encb, B2, encWb);

  for (int t = 0; t < 30; ++t) {
    k_scg<<<192, 256, 0, stream>>>(t, hx, B1, att1b, pa2, bd, bih, bhh, wf, bf, meta, geh, out, sc);
    k_gc<<<dim3(4, 64), 256, 0, stream>>>(t, sc, encWb, geh, B1, Wemb, meta, cbuf, hx, hh, pa2);
  }
  k_pred<<<1185, 256, 0, stream>>>(hh, Wfcb, bfc, meta, out);
}

// Round 14
// 2071.267 us; speedup vs baseline: 1.3142x; 1.0219x over previous
//
#include <hip/hip_runtime.h>
#include <cstdint>
#include <cstddef>

typedef __attribute__((ext_vector_type(8))) short short8;
typedef __attribute__((ext_vector_type(4))) float f32x4;

#define DEV static __device__ __forceinline__

#define PRED_ELEMS 19200000ULL   // 64*30*10000

// ---- workspace layout (bytes) ----
#define OFF_ENC   0ULL          // ushort [12544][2048] sorted enc bf16
#define OFF_ATT1  51380224ULL   // ushort [12544][512]
#define OFF_B1    64225280ULL   // ushort [2560][1024]  [Wd|0 ; Whh|Wih_e interleaved]
#define OFF_WFC   69468160ULL   // ushort [10016][512]  Wfc bf16, zero padded
#define OFF_WEB   79724544ULL   // ushort [512][2048]   We bf16
#define OFF_B0    81821696ULL   // ushort [1024][2048]  [Wh0;Wc0] (dead after k_h0c0)
#define OFF_HH    81821696ULL   // ushort [30][64][512] h history (reuses B0; 1.97MB)
#define OFF_PA2   83787776ULL   // float  [4][64][512]  partial att2 (512KB, in dead B0 gap)
#define OFF_B2    86016000ULL   // ushort [2048][2048]  Wih ctx-part, interleaved rows
#define OFF_HX    94404608ULL   // ushort [64][1024]    [h | e_t] bf16
#define OFF_C     94535680ULL   // float  [64][512]
#define OFF_GEH   94797824ULL   // float  [64][2048]    gates from h,e (interleaved 4d+q)
#define OFF_SC    95322112ULL   // float  [64][196]     alpha
#define OFF_CTX   95372288ULL   // ushort [64][2048]    (meanb during setup)
#define OFF_META  95634432ULL   // int: idx[64] dec[64] nact[32] caps[64*31]
#define OFF_ENCW  96000000ULL   // ushort [12544][2048] enc @ Wih_ctx^T (j-interleaved)

DEV float b2f(unsigned short u){ unsigned v = ((unsigned)u) << 16; float f; __builtin_memcpy(&f, &v, 4); return f; }
DEV unsigned short f2b(float x){ unsigned v; __builtin_memcpy(&v, &x, 4); unsigned r = v + 0x7fffu + ((v >> 16) & 1u); return (unsigned short)(r >> 16); }
DEV float sigm(float x){ return 1.0f / (1.0f + __expf(-x)); }
DEV float tanhf_fast(float x){ float e = __expf(2.0f * x); return 1.0f - 2.0f / (e + 1.0f); }

DEV void gload16(const void* g, void* l){
  __builtin_amdgcn_global_load_lds((const __attribute__((address_space(1))) unsigned int*)g,
                                   (__attribute__((address_space(3))) unsigned int*)l, 16, 0, 0);
}

// ---- LDS-staged 64x64 core (used only by one-time k_h0c0) ----
DEV void mm_core(const unsigned short* A, int ldA, int m0,
                 const unsigned short* Bm, int ldB, int n0,
                 int kIters, unsigned short* As, unsigned short* Bs, f32x4 acc[4])
{
  const int tid = threadIdx.x;
  const int lane = tid & 63, w = tid >> 6;
  const unsigned short* ga = A + (size_t)(m0 + lane) * ldA + w * 8;
  const unsigned short* gb = Bm + (size_t)(n0 + lane) * ldB + w * 8;
  unsigned short* la = As + w * 512;
  unsigned short* lb = Bs + w * 512;
  const int kb = lane >> 4, rr = lane & 15;
  for (int kk = 0; kk < kIters; ++kk) {
    gload16(ga, la); gload16(gb, lb);
    ga += 32; gb += 32;
    asm volatile("s_waitcnt vmcnt(0)" ::: "memory");
    __syncthreads();
    short8 bfr = *(const short8*)(Bs + (size_t)(kb * 64 + w * 16 + rr) * 8);
#pragma unroll
    for (int f = 0; f < 4; ++f) {
      short8 afr = *(const short8*)(As + (size_t)(kb * 64 + f * 16 + rr) * 8);
      acc[f] = __builtin_amdgcn_mfma_f32_16x16x32_bf16(afr, bfr, acc[f], 0, 0, 0);
    }
    __syncthreads();
  }
}

__global__ void k_meta(const int* __restrict__ caps, const int* __restrict__ lens, int* __restrict__ meta){
  int j = threadIdx.x;
  int lj = lens[j];
  int rank = 0;
  for (int k = 0; k < 64; ++k) { int lk = lens[k]; rank += (lk > lj) || (lk == lj && k < j); }
  meta[rank] = j; meta[64 + rank] = lj - 1;
  for (int t = 0; t < 31; ++t) meta[160 + rank * 31 + t] = caps[j * 31 + t];
  __syncthreads();
  if (j < 30) { int c = 0; for (int b = 0; b < 64; ++b) c += (meta[64 + b] > j); meta[128 + j] = c; }
}

__global__ __launch_bounds__(256) void k_encg(const float* __restrict__ enc, const int* __restrict__ meta, unsigned short* __restrict__ encb){
  int row = blockIdx.x; int b = row / 196, p = row % 196;
  const float* src = enc + ((size_t)meta[b] * 196 + p) * 2048;
  unsigned short* dst = encb + (size_t)row * 2048;
  int e0 = threadIdx.x * 8;
  short8 o;
#pragma unroll
  for (int j = 0; j < 8; ++j) o[j] = (short)f2b(src[e0 + j]);
  *(short8*)(dst + e0) = o;
}

__global__ __launch_bounds__(256) void k_wconv(const float* We, const float* Wh0, const float* Wc0,
                        const float* Wd, const float* Whh, const float* Wih, const float* Wfc,
                        unsigned short* Web, unsigned short* B0, unsigned short* B1,
                        unsigned short* Wfcb, unsigned short* B2){
  int bid = blockIdx.x, tid = threadIdx.x;
  if (bid < 512) {
    const float* s = We + (size_t)bid * 2048; unsigned short* d = Web + (size_t)bid * 2048;
    int e0 = tid * 8; short8 o;
#pragma unroll
    for (int j = 0; j < 8; ++j) o[j] = (short)f2b(s[e0 + j]);
    *(short8*)(d + e0) = o;
  } else if (bid < 1536) {
    int r = bid - 512;
    const float* s = (r < 512) ? (Wh0 + (size_t)r * 2048) : (Wc0 + (size_t)(r - 512) * 2048);
    unsigned short* d = B0 + (size_t)r * 2048;
    int e0 = tid * 8; short8 o;
#pragma unroll
    for (int j = 0; j < 8; ++j) o[j] = (short)f2b(s[e0 + j]);
    *(short8*)(d + e0) = o;
  } else if (bid < 3584) {   // B2: 2048 rows, j-interleaved (g = (j&3)*512 + (j>>2))
    int jr = bid - 1536; int g = (jr & 3) * 512 + (jr >> 2);
    const float* s = Wih + (size_t)g * 2560 + 512;
    unsigned short* d = B2 + (size_t)jr * 2048;
    int e0 = tid * 8; short8 o;
#pragma unroll
    for (int j = 0; j < 8; ++j) o[j] = (short)f2b(s[e0 + j]);
    *(short8*)(d + e0) = o;
  } else if (bid < 6144) {   // B1: 2560 rows
    int n = bid - 3584; unsigned short* d = B1 + (size_t)n * 1024;
    int k0 = tid * 4;
    if (n < 512) {
#pragma unroll
      for (int j = 0; j < 4; ++j) { int k = k0 + j; d[k] = (k < 512) ? f2b(Wd[(size_t)n * 512 + k]) : (unsigned short)0; }
    } else {
      int j2 = n - 512; int g = (j2 & 3) * 512 + (j2 >> 2);
#pragma unroll
      for (int j = 0; j < 4; ++j) { int k = k0 + j;
        d[k] = (k < 512) ? f2b(Whh[(size_t)g * 512 + k]) : f2b(Wih[(size_t)g * 2560 + (k - 512)]); }
    }
  } else {                   // Wfcb: 10016 rows
    int v = bid - 6144; unsigned short* d = Wfcb + (size_t)v * 512;
    int k0 = tid * 2;
#pragma unroll
    for (int j = 0; j < 2; ++j) d[k0 + j] = (v < 10000) ? f2b(Wfc[(size_t)v * 512 + k0 + j]) : (unsigned short)0;
  }
}

__global__ __launch_bounds__(256) void k_mean(const unsigned short* __restrict__ encb, unsigned short* __restrict__ meanb){
  int b = blockIdx.y, ch = blockIdx.x;
  int e = ch * 512 + threadIdx.x * 2;
  const unsigned short* ep = encb + (size_t)b * 196 * 2048 + e;
  float s0 = 0.f, s1 = 0.f;
  for (int p = 0; p < 196; ++p) {
    unsigned u = *(const unsigned*)(ep + (size_t)p * 2048);
    s0 += b2f((unsigned short)(u & 0xffff));
    s1 += b2f((unsigned short)(u >> 16));
  }
  const float inv = 1.0f / 196.0f;
  unsigned o = ((unsigned)f2b(s1 * inv) << 16) | f2b(s0 * inv);
  *(unsigned*)(meanb + (size_t)b * 2048 + e) = o;
}

__global__ __launch_bounds__(256) void k_h0c0(const unsigned short* meanb, const unsigned short* B0,
                      const float* bh0, const float* bc0, unsigned short* hx, float* cbuf){
  __shared__ __align__(16) unsigned short As[2048], Bs[2048];
  f32x4 acc[4];
#pragma unroll
  for (int f = 0; f < 4; ++f) acc[f] = (f32x4){0.f,0.f,0.f,0.f};
  int nt = blockIdx.x;
  mm_core(meanb, 2048, 0, B0, 2048, nt * 64, 64, As, Bs, acc);
  int lane = threadIdx.x & 63, w = threadIdx.x >> 6;
  int col = lane & 15, rhi = lane >> 4;
  int n = nt * 64 + w * 16 + col;
#pragma unroll
  for (int f = 0; f < 4; ++f)
#pragma unroll
    for (int r = 0; r < 4; ++r) {
      int b = f * 16 + rhi * 4 + r; float v = acc[f][r];
      if (n < 512) hx[(size_t)b * 1024 + n] = f2b(v + bh0[n]);
      else cbuf[(size_t)b * 512 + (n - 512)] = v + bc0[n - 512];
    }
}

__global__ void k_emb0(const float* __restrict__ Wemb, const int* __restrict__ meta, unsigned short* __restrict__ hx){
  int b = blockIdx.x;
  int cap = meta[160 + b * 31];
  for (int j = threadIdx.x; j < 512; j += 256)
    hx[(size_t)b * 1024 + 512 + j] = f2b(Wemb[(size_t)cap * 512 + j]);
}

// ---- k_big: enc @ [Web;B2]^T one-shot, 98m x 20n tiles, XCD-grouped.
//      nt<4 -> att1b (+be); nt>=4 -> encW ----
__global__ __launch_bounds__(256) void k_big(const unsigned short* __restrict__ encb,
                      const unsigned short* __restrict__ Web, const unsigned short* __restrict__ B2,
                      const float* __restrict__ be,
                      unsigned short* __restrict__ att1b, unsigned short* __restrict__ encW){
  __shared__ __align__(16) unsigned short As[2][4096], Bs[2][4096];
  int tid = threadIdx.x, lane = tid & 63, w = tid >> 6;
  int xcd = blockIdx.x & 7, slot = blockIdx.x >> 3;
  int mtl = slot / 20, nt = slot % 20;
  int mt = mtl * 8 + xcd;
  if (mt >= 98) return;
  int wr = (w >> 1) * 64, wc = (w & 1) * 64;
  int rr = lane & 15, kb = lane >> 4;
  f32x4 acc[4][4];
#pragma unroll
  for (int f = 0; f < 4; ++f)
#pragma unroll
    for (int q = 0; q < 4; ++q) acc[f][q] = (f32x4){0.f,0.f,0.f,0.f};

  const unsigned short* gA = encb + (size_t)mt * 128 * 2048;
  const unsigned short* gB = (nt < 4) ? (Web + (size_t)nt * 128 * 2048)
                                      : (B2 + (size_t)(nt - 4) * 128 * 2048);
  int L0 = tid, L1 = tid + 256;
  size_t s0 = (size_t)(L0 & 127) * 2048 + ((L0 >> 7) << 3);
  size_t s1 = (size_t)(L1 & 127) * 2048 + ((L1 >> 7) << 3);
  int d0 = (w * 64) * 8, d1 = (w * 64 + 256) * 8;

#define STAGE_B(kk, bf) do { \
    gload16(gA + s0 + (size_t)(kk) * 32, &As[bf][d0]); \
    gload16(gB + s0 + (size_t)(kk) * 32, &Bs[bf][d0]); \
    gload16(gA + s1 + (size_t)(kk) * 32, &As[bf][d1]); \
    gload16(gB + s1 + (size_t)(kk) * 32, &Bs[bf][d1]); \
  } while (0)

  STAGE_B(0, 0);
  __syncthreads();
  for (int kk = 0; kk < 64; ++kk) {
    int cur = kk & 1;
    if (kk < 63) STAGE_B(kk + 1, cur ^ 1);
    short8 af[4], bq[4];
#pragma unroll
    for (int f = 0; f < 4; ++f)
      af[f] = *(const short8*)&As[cur][((kb << 7) + wr + f * 16 + rr) * 8];
#pragma unroll
    for (int q = 0; q < 4; ++q)
      bq[q] = *(const short8*)&Bs[cur][((kb << 7) + wc + q * 16 + rr) * 8];
#pragma unroll
    for (int f = 0; f < 4; ++f)
#pragma unroll
      for (int q = 0; q < 4; ++q)
        acc[f][q] = __builtin_amdgcn_mfma_f32_16x16x32_bf16(af[f], bq[q], acc[f][q], 0, 0, 0);
    __syncthreads();
  }
#undef STAGE_B
  int col = lane & 15, rhi = lane >> 4;
  if (nt < 4) {
#pragma unroll
    for (int q = 0; q < 4; ++q) {
      int n = nt * 128 + wc + q * 16 + col;
      float bev = be[n];
#pragma unroll
      for (int f = 0; f < 4; ++f)
#pragma unroll
        for (int r = 0; r < 4; ++r) {
          int m = mt * 128 + wr + f * 16 + rhi * 4 + r;
          att1b[(size_t)m * 512 + n] = f2b(acc[f][q][r] + bev);
        }
    }
  } else {
#pragma unroll
    for (int q = 0; q < 4; ++q) {
      int n = (nt - 4) * 128 + wc + q * 16 + col;
#pragma unroll
      for (int f = 0; f < 4; ++f)
#pragma unroll
        for (int r = 0; r < 4; ++r) {
          int m = mt * 128 + wr + f * 16 + rhi * 4 + r;
          encW[(size_t)m * 2048 + n] = f2b(acc[f][q][r]);
        }
    }
  }
}

// ---- k_att2i (init only): pa2[0] = h0 @ Wd^T (no bias), 8 blocks x 4 waves ----
__global__ __launch_bounds__(256) void k_att2i(const unsigned short* __restrict__ hx,
                      const unsigned short* __restrict__ B1, float* __restrict__ pa2){
  int w = threadIdx.x >> 6, lane = threadIdx.x & 63;
  int omega = blockIdx.x * 4 + w;   // 0..31
  int rr = lane & 15, kb8 = (lane >> 4) * 8;
  const unsigned short* pb = B1 + (size_t)(omega * 16 + rr) * 1024 + kb8;
  const unsigned short* pa0 = hx + (size_t)rr * 1024 + kb8;
  f32x4 acc[4];
#pragma unroll
  for (int f = 0; f < 4; ++f) acc[f] = (f32x4){0.f,0.f,0.f,0.f};
#pragma unroll 4
  for (int kk = 0; kk < 16; ++kk) {
    short8 bfr = *(const short8*)(pb + kk * 32);
#pragma unroll
    for (int f = 0; f < 4; ++f) {
      short8 afr = *(const short8*)(pa0 + (size_t)f * 16384 + kk * 32);
      acc[f] = __builtin_amdgcn_mfma_f32_16x16x32_bf16(afr, bfr, acc[f], 0, 0, 0);
    }
  }
  int col = lane & 15, rhi = lane >> 4;
  int n = omega * 16 + col;
#pragma unroll
  for (int f = 0; f < 4; ++f)
#pragma unroll
    for (int r = 0; r < 4; ++r) { int b = f * 16 + rhi * 4 + r; pa2[(size_t)b * 512 + n] = acc[f][r]; }
}

// ---- k_scg: blocks 0-63 = per-b [sum pa2 -> a2s] + all-196 scores + softmax + alpha;
//             blocks 64-191 = gates_he wave-GEMM ----
__global__ __launch_bounds__(256) void k_scg(int t, const unsigned short* __restrict__ hx,
                      const unsigned short* __restrict__ B1, const unsigned short* __restrict__ att1b,
                      const float* __restrict__ pa2,
                      const float* __restrict__ bd, const float* __restrict__ bih, const float* __restrict__ bhh,
                      const float* __restrict__ wf, const float* __restrict__ bfp,
                      const int* __restrict__ meta,
                      float* __restrict__ geh, float* __restrict__ out, float* __restrict__ alp){
  int bid = blockIdx.x;
  int tid = threadIdx.x, lane = tid & 63, w = tid >> 6;
  int rr = lane & 15, kb8 = (lane >> 4) * 8;
  if (bid >= 64) {
    // ---- gates_he wave GEMM (non-redundant) ----
    int jblk = bid - 64;
    const unsigned short* pb = B1 + (size_t)(512 + jblk * 16 + rr) * 1024 + kb8;
    const unsigned short* pa0 = hx + (size_t)rr * 1024 + kb8;
    f32x4 acc[4];
#pragma unroll
    for (int f = 0; f < 4; ++f) acc[f] = (f32x4){0.f,0.f,0.f,0.f};
#pragma unroll 4
    for (int kk = 0; kk < 32; ++kk) {
      short8 bfr = *(const short8*)(pb + kk * 32);
#pragma unroll
      for (int f = 0; f < 4; ++f) {
        short8 afr = *(const short8*)(pa0 + (size_t)f * 16384 + kk * 32);
        acc[f] = __builtin_amdgcn_mfma_f32_16x16x32_bf16(afr, bfr, acc[f], 0, 0, 0);
      }
    }
    int col = lane & 15, rhi = lane >> 4;
    int j = jblk * 16 + col; int g = (j & 3) * 512 + (j >> 2);
    float bv = bih[g] + bhh[g];
#pragma unroll
    for (int f = 0; f < 4; ++f)
#pragma unroll
      for (int r = 0; r < 4; ++r) { int b = f * 16 + rhi * 4 + r; geh[(size_t)b * 2048 + j] = acc[f][r] + bv; }
    return;
  }
  // ---- per-b: sum partial att2 + scores + softmax ----
  int b = bid;
  if (b >= meta[128 + t]) return;
  __shared__ float a2s[512];
  __shared__ float sal[200];
  __shared__ float red[256];
#pragma unroll
  for (int r = 0; r < 2; ++r) {
    int n = tid + r * 256;
    a2s[n] = pa2[(size_t)b * 512 + n] + pa2[(size_t)(64 + b) * 512 + n]
           + pa2[(size_t)(128 + b) * 512 + n] + pa2[(size_t)(192 + b) * 512 + n] + bd[n];
  }
  __syncthreads();
  {
    float wfr[8], a2[8];
#pragma unroll
    for (int j = 0; j < 8; ++j) { wfr[j] = wf[lane * 8 + j]; a2[j] = a2s[lane * 8 + j]; }
    float bf0 = bfp[0];
    for (int i = 0; i < 49; ++i) {
      int p = i * 4 + w;
      short8 av = *(const short8*)(att1b + ((size_t)(b * 196 + p)) * 512 + lane * 8);
      float s = 0.f;
#pragma unroll
      for (int j = 0; j < 8; ++j) s += tanhf_fast(b2f((unsigned short)av[j]) + a2[j]) * wfr[j];
#pragma unroll
      for (int off = 32; off; off >>= 1) s += __shfl_xor(s, off);
      if (lane == 0) sal[p] = s + bf0;
    }
  }
  __syncthreads();
  {
    float v = (tid < 196) ? sal[tid] : -3.0e38f;
    red[tid] = v; __syncthreads();
    for (int s = 128; s; s >>= 1) { if (tid < s) red[tid] = fmaxf(red[tid], red[tid + s]); __syncthreads(); }
    float mx = red[0]; __syncthreads();
    float ex = (tid < 196) ? __expf(v - mx) : 0.f;
    red[tid] = ex; __syncthreads();
    for (int s = 128; s; s >>= 1) { if (tid < s) red[tid] += red[tid + s]; __syncthreads(); }
    float inv = 1.0f / red[0];
    if (tid < 196) {
      float al = ex * inv;
      alp[(size_t)b * 196 + tid] = al;
      out[PRED_ELEMS + ((size_t)b * 30 + t) * 196 + tid] = al;
    }
  }
}

// ---- k_gc: gates_ctx = alpha@encW + geh + cell + hh + emb + MFMA pa2 push ----
__global__ __launch_bounds__(256) void k_gc(int t, const float* __restrict__ alp,
                      const unsigned short* __restrict__ encW, const float* __restrict__ geh,
                      const unsigned short* __restrict__ B1,
                      const float* __restrict__ Wemb, const int* __restrict__ meta,
                      float* __restrict__ cbuf, unsigned short* __restrict__ hx,
                      unsigned short* __restrict__ hh, float* __restrict__ pa2){
  int b = blockIdx.y, ch = blockIdx.x;
  int tid = threadIdx.x, lane = tid & 63, w = tid >> 6;
  int na = meta[128 + t];
  __shared__ float sal[200];
  __shared__ float part[4][512];
  __shared__ float gt[512];
  __shared__ __align__(16) unsigned short hsb[128];

  if (b < na) {
    if (tid < 196) sal[tid] = alp[(size_t)b * 196 + tid];
    __syncthreads();
    const unsigned short* ep = encW + ((size_t)b * 196) * 2048 + ch * 512 + lane * 8;
    float s8[8];
#pragma unroll
    for (int j = 0; j < 8; ++j) s8[j] = 0.f;
#pragma unroll 7
    for (int i = 0; i < 49; ++i) {
      int p = w + i * 4;
      short8 vv = *(const short8*)(ep + (size_t)p * 2048);
      float a = sal[p];
#pragma unroll
      for (int j = 0; j < 8; ++j) s8[j] += a * b2f((unsigned short)vv[j]);
    }
#pragma unroll
    for (int j = 0; j < 8; ++j) part[w][lane * 8 + j] = s8[j];
    __syncthreads();
    int j0 = tid * 2;
    gt[j0]     = part[0][j0] + part[1][j0] + part[2][j0] + part[3][j0]
               + geh[(size_t)b * 2048 + ch * 512 + j0];
    gt[j0 + 1] = part[0][j0 + 1] + part[1][j0 + 1] + part[2][j0 + 1] + part[3][j0 + 1]
               + geh[(size_t)b * 2048 + ch * 512 + j0 + 1];
    __syncthreads();

    if (tid < 128) {
      int d = ch * 128 + tid;
      float ig = gt[tid * 4 + 0];
      float fg = gt[tid * 4 + 1];
      float gg = gt[tid * 4 + 2];
      float og = gt[tid * 4 + 3];
      float c0 = cbuf[(size_t)b * 512 + d];
      float ct = sigm(fg) * c0 + sigm(ig) * tanhf_fast(gg);
      float ht = sigm(og) * tanhf_fast(ct);
      cbuf[(size_t)b * 512 + d] = ct;
      unsigned short hb = f2b(ht);
      hsb[tid] = hb;
      hx[(size_t)b * 1024 + d] = hb;
      hh[((size_t)t * 64 + b) * 512 + d] = hb;
      int cap = meta[160 + b * 31 + t + 1];
      hx[(size_t)b * 1024 + 512 + d] = f2b(Wemb[(size_t)cap * 512 + d]);
    }
  } else {
    if (tid < 128) {
      int d = ch * 128 + tid;
      unsigned short hold = hx[(size_t)b * 1024 + d];
      hsb[tid] = hold;
      hh[((size_t)t * 64 + b) * 512 + d] = hold;
      int cap = meta[160 + b * 31 + t + 1];
      hx[(size_t)b * 1024 + 512 + d] = f2b(Wemb[(size_t)cap * 512 + d]);
    }
  }
  __syncthreads();
  // ---- MFMA pa2 push: pa2[ch][b][n] = sum_{k<128} hsb[k] * Wd[n][ch*128+k] ----
  {
    int rr = lane & 15, kb8 = (lane >> 4) * 8;
    f32x4 pacc[8];
#pragma unroll
    for (int q = 0; q < 8; ++q) pacc[q] = (f32x4){0.f,0.f,0.f,0.f};
#pragma unroll
    for (int kk = 0; kk < 4; ++kk) {
      short8 afr = *(const short8*)(hsb + kk * 32 + kb8);   // broadcast-A: all rows = h slice
#pragma unroll
      for (int q = 0; q < 8; ++q) {
        const unsigned short* bp = B1 + (size_t)(w * 128 + q * 16 + rr) * 1024 + ch * 128 + kk * 32 + kb8;
        short8 bfr = *(const short8*)bp;
        pacc[q] = __builtin_amdgcn_mfma_f32_16x16x32_bf16(afr, bfr, pacc[q], 0, 0, 0);
      }
    }
    if (lane < 16) {
      float* pd = pa2 + ((size_t)ch * 64 + b) * 512 + w * 128 + lane;
#pragma unroll
      for (int q = 0; q < 8; ++q) pd[q * 16] = pacc[q][0];
    }
  }
}

// ---- pred: all-steps batched GEMM hh[1920x512] @ Wfcb^T -> out (masked) ----
__global__ __launch_bounds__(256) void k_pred(const unsigned short* __restrict__ hh,
                      const unsigned short* __restrict__ Wfcb, const float* __restrict__ bfc,
                      const int* __restrict__ meta, float* __restrict__ out){
  __shared__ __align__(16) unsigned short As[2][4096], Bs[2][4096];
  int tid = threadIdx.x, lane = tid & 63, w = tid >> 6;
  int mt = blockIdx.x % 15, nt = blockIdx.x / 15;   // 15 x 79
  int wr = (w >> 1) * 64, wc = (w & 1) * 64;
  int rr = lane & 15, kb = lane >> 4;
  f32x4 acc[4][4];
#pragma unroll
  for (int f = 0; f < 4; ++f)
#pragma unroll
    for (int q = 0; q < 4; ++q) acc[f][q] = (f32x4){0.f,0.f,0.f,0.f};

  const unsigned short* gA = hh + (size_t)mt * 128 * 512;
  int L0 = tid, L1 = tid + 256;
  size_t sa0 = (size_t)(L0 & 127) * 512 + ((L0 >> 7) << 3);
  size_t sa1 = (size_t)(L1 & 127) * 512 + ((L1 >> 7) << 3);
  int br0 = nt * 128 + (L0 & 127); if (br0 > 10015) br0 = 10015;
  int br1 = nt * 128 + (L1 & 127); if (br1 > 10015) br1 = 10015;
  size_t sb0 = (size_t)br0 * 512 + ((L0 >> 7) << 3);
  size_t sb1 = (size_t)br1 * 512 + ((L1 >> 7) << 3);
  int d0 = (w * 64) * 8, d1 = (w * 64 + 256) * 8;

#define STAGE_P(kk, bf) do { \
    gload16(gA + sa0 + (size_t)(kk) * 32, &As[bf][d0]); \
    gload16(Wfcb + sb0 + (size_t)(kk) * 32, &Bs[bf][d0]); \
    gload16(gA + sa1 + (size_t)(kk) * 32, &As[bf][d1]); \
    gload16(Wfcb + sb1 + (size_t)(kk) * 32, &Bs[bf][d1]); \
  } while (0)

  STAGE_P(0, 0);
  __syncthreads();
  for (int kk = 0; kk < 16; ++kk) {
    int cur = kk & 1;
    if (kk < 15) STAGE_P(kk + 1, cur ^ 1);
    short8 af[4], bq[4];
#pragma unroll
    for (int f = 0; f < 4; ++f)
      af[f] = *(const short8*)&As[cur][((kb << 7) + wr + f * 16 + rr) * 8];
#pragma unroll
    for (int q = 0; q < 4; ++q)
      bq[q] = *(const short8*)&Bs[cur][((kb << 7) + wc + q * 16 + rr) * 8];
#pragma unroll
    for (int f = 0; f < 4; ++f)
#pragma unroll
      for (int q = 0; q < 4; ++q)
        acc[f][q] = __builtin_amdgcn_mfma_f32_16x16x32_bf16(af[f], bq[q], acc[f][q], 0, 0, 0);
    __syncthreads();
  }
#undef STAGE_P
  int col = lane & 15, rhi = lane >> 4;
  int tt = mt * 2 + (wr >> 6);
  int na = meta[128 + tt];
#pragma unroll
  for (int q = 0; q < 4; ++q) {
    int n = nt * 128 + wc + q * 16 + col;
    if (n >= 10000) continue;
    float bv = bfc[n];
#pragma unroll
    for (int f = 0; f < 4; ++f)
#pragma unroll
      for (int r = 0; r < 4; ++r) {
        int b = f * 16 + rhi * 4 + r;
        if (b < na) out[(size_t)b * 300000 + (size_t)tt * 10000 + n] = acc[f][q][r] + bv;
      }
  }
}

extern "C" void kernel_launch(void* const* d_in, const int* in_sizes, int n_in,
                              void* d_out, int out_size, void* d_ws, size_t ws_size,
                              hipStream_t stream) {
  (void)in_sizes; (void)n_in; (void)ws_size;
  const float* enc  = (const float*)d_in[0];
  const int*   caps = (const int*)d_in[1];
  const int*   lens = (const int*)d_in[2];
  const float* Wemb = (const float*)d_in[3];
  const float* We   = (const float*)d_in[4];
  const float* be   = (const float*)d_in[5];
  const float* Wd   = (const float*)d_in[6];
  const float* bd   = (const float*)d_in[7];
  const float* wf   = (const float*)d_in[8];
  const float* bf   = (const float*)d_in[9];
  const float* Wih  = (const float*)d_in[10];
  const float* bih  = (const float*)d_in[11];
  const float* Whh  = (const float*)d_in[12];
  const float* bhh  = (const float*)d_in[13];
  const float* Wfc  = (const float*)d_in[14];
  const float* bfc  = (const float*)d_in[15];
  const float* Wh0  = (const float*)d_in[16];
  const float* bh0  = (const float*)d_in[17];
  const float* Wc0  = (const float*)d_in[18];
  const float* bc0  = (const float*)d_in[19];

  char* ws = (char*)d_ws;
  unsigned short* encb  = (unsigned short*)(ws + OFF_ENC);
  unsigned short* att1b = (unsigned short*)(ws + OFF_ATT1);
  unsigned short* B1    = (unsigned short*)(ws + OFF_B1);
  unsigned short* Wfcb  = (unsigned short*)(ws + OFF_WFC);
  unsigned short* Web   = (unsigned short*)(ws + OFF_WEB);
  unsigned short* B0    = (unsigned short*)(ws + OFF_B0);
  unsigned short* hh    = (unsigned short*)(ws + OFF_HH);
  float*          pa2   = (float*)(ws + OFF_PA2);
  unsigned short* B2    = (unsigned short*)(ws + OFF_B2);
  unsigned short* hx    = (unsigned short*)(ws + OFF_HX);
  float*          cbuf  = (float*)(ws + OFF_C);
  float*          geh   = (float*)(ws + OFF_GEH);
  float*          sc    = (float*)(ws + OFF_SC);
  unsigned short* ctxb  = (unsigned short*)(ws + OFF_CTX);
  int*            meta  = (int*)(ws + OFF_META);
  unsigned short* encWb = (unsigned short*)(ws + OFF_ENCW);
  unsigned short* meanb = ctxb;   // setup-time only
  float* out = (float*)d_out;

  hipMemsetAsync(d_out, 0, (size_t)out_size * sizeof(float), stream);
  k_meta<<<1, 64, 0, stream>>>(caps, lens, meta);
  k_encg<<<12544, 256, 0, stream>>>(enc, meta, encb);
  k_wconv<<<16160, 256, 0, stream>>>(We, Wh0, Wc0, Wd, Whh, Wih, Wfc, Web, B0, B1, Wfcb, B2);
  k_mean<<<dim3(4, 64), 256, 0, stream>>>(encb, meanb);
  k_h0c0<<<16, 256, 0, stream>>>(meanb, B0, bh0, bc0, hx, cbuf);
  k_emb0<<<64, 256, 0, stream>>>(Wemb, meta, hx);
  // init pa2: slice 0 = full h0@Wd^T, slices 1..3 = 0
  hipMemsetAsync(pa2 + 64 * 512, 0, 3 * 64 * 512 * sizeof(float), stream);
  k_att2i<<<8, 256, 0, stream>>>(hx, B1, pa2);
  k_big<<<2080, 256, 0, stream>>>(encb, Web, B2, be, att1b, encWb);

  for (int t = 0; t < 30; ++t) {
    k_scg<<<192, 256, 0, stream>>>(t, hx, B1, att1b, pa2, bd, bih, bhh, wf, bf, meta, geh, out, sc);
    k_gc<<<dim3(4, 64), 256, 0, stream>>>(t, sc, encWb, geh, B1, Wemb, meta, cbuf, hx, hh, pa2);
  }
  k_pred<<<1185, 256, 0, stream>>>(hh, Wfcb, bfc, meta, out);
}

// Round 15
// 1781.889 us; speedup vs baseline: 1.5276x; 1.1624x over previous
//
#include <hip/hip_runtime.h>
#include <cstdint>
#include <cstddef>

typedef __attribute__((ext_vector_type(8))) short short8;
typedef __attribute__((ext_vector_type(4))) float f32x4;

#define DEV static __device__ __forceinline__

#define PRED_ELEMS 19200000ULL   // 64*30*10000

// ---- workspace layout (bytes) ----
#define OFF_ENC   0ULL          // ushort [12544][2048] sorted enc bf16
#define OFF_ATT1  51380224ULL   // ushort [12544][512]
#define OFF_B1    64225280ULL   // ushort [2560][1024]  [Wd|0 ; Whh|Wih_e interleaved]
#define OFF_WFC   69468160ULL   // ushort [10016][512]  Wfc bf16, zero padded
#define OFF_WEB   79724544ULL   // ushort [512][2048]   We bf16
#define OFF_B0    81821696ULL   // ushort [1024][2048]  [Wh0;Wc0] (dead after k_h0c0)
#define OFF_HH    81821696ULL   // ushort [30][64][512] h history (reuses B0)
#define OFF_B2    86016000ULL   // ushort [2048][2048]  Wih ctx-part, interleaved rows
#define OFF_HX    94404608ULL   // ushort [64][1024]    [h | e_t] bf16
#define OFF_C     94535680ULL   // float  [64][512]
#define OFF_ATT2  94666752ULL   // float  [64][512]
#define OFF_GEH   94797824ULL   // float  [64][2048]    gates from h,e (interleaved 4d+q)
#define OFF_SC    95322112ULL   // float  [64][196]     alpha
#define OFF_CTX   95372288ULL   // ushort [64][2048]    (meanb during setup)
#define OFF_META  95634432ULL   // int: idx[64] dec[64] nact[32] caps[64*31]
#define OFF_ENCW  96000000ULL   // ushort [12544][2048] enc @ Wih_ctx^T (j-interleaved)

DEV float b2f(unsigned short u){ unsigned v = ((unsigned)u) << 16; float f; __builtin_memcpy(&f, &v, 4); return f; }
DEV unsigned short f2b(float x){ unsigned v; __builtin_memcpy(&v, &x, 4); unsigned r = v + 0x7fffu + ((v >> 16) & 1u); return (unsigned short)(r >> 16); }
DEV float sigm(float x){ return 1.0f / (1.0f + __expf(-x)); }
DEV float tanhf_fast(float x){ float e = __expf(2.0f * x); return 1.0f - 2.0f / (e + 1.0f); }

DEV void gload16(const void* g, void* l){
  __builtin_amdgcn_global_load_lds((const __attribute__((address_space(1))) unsigned int*)g,
                                   (__attribute__((address_space(3))) unsigned int*)l, 16, 0, 0);
}

// ---- LDS-staged 64x64 core (used only by one-time k_h0c0) ----
DEV void mm_core(const unsigned short* A, int ldA, int m0,
                 const unsigned short* Bm, int ldB, int n0,
                 int kIters, unsigned short* As, unsigned short* Bs, f32x4 acc[4])
{
  const int tid = threadIdx.x;
  const int lane = tid & 63, w = tid >> 6;
  const unsigned short* ga = A + (size_t)(m0 + lane) * ldA + w * 8;
  const unsigned short* gb = Bm + (size_t)(n0 + lane) * ldB + w * 8;
  unsigned short* la = As + w * 512;
  unsigned short* lb = Bs + w * 512;
  const int kb = lane >> 4, rr = lane & 15;
  for (int kk = 0; kk < kIters; ++kk) {
    gload16(ga, la); gload16(gb, lb);
    ga += 32; gb += 32;
    asm volatile("s_waitcnt vmcnt(0)" ::: "memory");
    __syncthreads();
    short8 bfr = *(const short8*)(Bs + (size_t)(kb * 64 + w * 16 + rr) * 8);
#pragma unroll
    for (int f = 0; f < 4; ++f) {
      short8 afr = *(const short8*)(As + (size_t)(kb * 64 + f * 16 + rr) * 8);
      acc[f] = __builtin_amdgcn_mfma_f32_16x16x32_bf16(afr, bfr, acc[f], 0, 0, 0);
    }
    __syncthreads();
  }
}

__global__ void k_meta(const int* __restrict__ caps, const int* __restrict__ lens, int* __restrict__ meta){
  int j = threadIdx.x;
  int lj = lens[j];
  int rank = 0;
  for (int k = 0; k < 64; ++k) { int lk = lens[k]; rank += (lk > lj) || (lk == lj && k < j); }
  meta[rank] = j; meta[64 + rank] = lj - 1;
  for (int t = 0; t < 31; ++t) meta[160 + rank * 31 + t] = caps[j * 31 + t];
  __syncthreads();
  if (j < 30) { int c = 0; for (int b = 0; b < 64; ++b) c += (meta[64 + b] > j); meta[128 + j] = c; }
}

__global__ __launch_bounds__(256) void k_encg(const float* __restrict__ enc, const int* __restrict__ meta, unsigned short* __restrict__ encb){
  int row = blockIdx.x; int b = row / 196, p = row % 196;
  const float* src = enc + ((size_t)meta[b] * 196 + p) * 2048;
  unsigned short* dst = encb + (size_t)row * 2048;
  int e0 = threadIdx.x * 8;
  short8 o;
#pragma unroll
  for (int j = 0; j < 8; ++j) o[j] = (short)f2b(src[e0 + j]);
  *(short8*)(dst + e0) = o;
}

__global__ __launch_bounds__(256) void k_wconv(const float* We, const float* Wh0, const float* Wc0,
                        const float* Wd, const float* Whh, const float* Wih, const float* Wfc,
                        unsigned short* Web, unsigned short* B0, unsigned short* B1,
                        unsigned short* Wfcb, unsigned short* B2){
  int bid = blockIdx.x, tid = threadIdx.x;
  if (bid < 512) {
    const float* s = We + (size_t)bid * 2048; unsigned short* d = Web + (size_t)bid * 2048;
    int e0 = tid * 8; short8 o;
#pragma unroll
    for (int j = 0; j < 8; ++j) o[j] = (short)f2b(s[e0 + j]);
    *(short8*)(d + e0) = o;
  } else if (bid < 1536) {
    int r = bid - 512;
    const float* s = (r < 512) ? (Wh0 + (size_t)r * 2048) : (Wc0 + (size_t)(r - 512) * 2048);
    unsigned short* d = B0 + (size_t)r * 2048;
    int e0 = tid * 8; short8 o;
#pragma unroll
    for (int j = 0; j < 8; ++j) o[j] = (short)f2b(s[e0 + j]);
    *(short8*)(d + e0) = o;
  } else if (bid < 3584) {   // B2: 2048 rows, j-interleaved (g = (j&3)*512 + (j>>2))
    int jr = bid - 1536; int g = (jr & 3) * 512 + (jr >> 2);
    const float* s = Wih + (size_t)g * 2560 + 512;
    unsigned short* d = B2 + (size_t)jr * 2048;
    int e0 = tid * 8; short8 o;
#pragma unroll
    for (int j = 0; j < 8; ++j) o[j] = (short)f2b(s[e0 + j]);
    *(short8*)(d + e0) = o;
  } else if (bid < 6144) {   // B1: 2560 rows
    int n = bid - 3584; unsigned short* d = B1 + (size_t)n * 1024;
    int k0 = tid * 4;
    if (n < 512) {
#pragma unroll
      for (int j = 0; j < 4; ++j) { int k = k0 + j; d[k] = (k < 512) ? f2b(Wd[(size_t)n * 512 + k]) : (unsigned short)0; }
    } else {
      int j2 = n - 512; int g = (j2 & 3) * 512 + (j2 >> 2);
#pragma unroll
      for (int j = 0; j < 4; ++j) { int k = k0 + j;
        d[k] = (k < 512) ? f2b(Whh[(size_t)g * 512 + k]) : f2b(Wih[(size_t)g * 2560 + (k - 512)]); }
    }
  } else {                   // Wfcb: 10016 rows
    int v = bid - 6144; unsigned short* d = Wfcb + (size_t)v * 512;
    int k0 = tid * 2;
#pragma unroll
    for (int j = 0; j < 2; ++j) d[k0 + j] = (v < 10000) ? f2b(Wfc[(size_t)v * 512 + k0 + j]) : (unsigned short)0;
  }
}

__global__ __launch_bounds__(256) void k_mean(const unsigned short* __restrict__ encb, unsigned short* __restrict__ meanb){
  int b = blockIdx.y, ch = blockIdx.x;
  int e = ch * 512 + threadIdx.x * 2;
  const unsigned short* ep = encb + (size_t)b * 196 * 2048 + e;
  float s0 = 0.f, s1 = 0.f;
  for (int p = 0; p < 196; ++p) {
    unsigned u = *(const unsigned*)(ep + (size_t)p * 2048);
    s0 += b2f((unsigned short)(u & 0xffff));
    s1 += b2f((unsigned short)(u >> 16));
  }
  const float inv = 1.0f / 196.0f;
  unsigned o = ((unsigned)f2b(s1 * inv) << 16) | f2b(s0 * inv);
  *(unsigned*)(meanb + (size_t)b * 2048 + e) = o;
}

__global__ __launch_bounds__(256) void k_h0c0(const unsigned short* meanb, const unsigned short* B0,
                      const float* bh0, const float* bc0, unsigned short* hx, float* cbuf){
  __shared__ __align__(16) unsigned short As[2048], Bs[2048];
  f32x4 acc[4];
#pragma unroll
  for (int f = 0; f < 4; ++f) acc[f] = (f32x4){0.f,0.f,0.f,0.f};
  int nt = blockIdx.x;
  mm_core(meanb, 2048, 0, B0, 2048, nt * 64, 64, As, Bs, acc);
  int lane = threadIdx.x & 63, w = threadIdx.x >> 6;
  int col = lane & 15, rhi = lane >> 4;
  int n = nt * 64 + w * 16 + col;
#pragma unroll
  for (int f = 0; f < 4; ++f)
#pragma unroll
    for (int r = 0; r < 4; ++r) {
      int b = f * 16 + rhi * 4 + r; float v = acc[f][r];
      if (n < 512) hx[(size_t)b * 1024 + n] = f2b(v + bh0[n]);
      else cbuf[(size_t)b * 512 + (n - 512)] = v + bc0[n - 512];
    }
}

__global__ void k_emb0(const float* __restrict__ Wemb, const int* __restrict__ meta, unsigned short* __restrict__ hx){
  int b = blockIdx.x;
  int cap = meta[160 + b * 31];
  for (int j = threadIdx.x; j < 512; j += 256)
    hx[(size_t)b * 1024 + 512 + j] = f2b(Wemb[(size_t)cap * 512 + j]);
}

// ---- att1: 128x128 tile GEMM with XCD-grouped block swizzle (R11-proven) ----
__global__ __launch_bounds__(256) void k_att1(const unsigned short* __restrict__ encb,
                      const unsigned short* __restrict__ Web,
                      const float* __restrict__ be, unsigned short* __restrict__ att1b){
  __shared__ __align__(16) unsigned short As[2][4096], Bs[2][4096];
  int tid = threadIdx.x, lane = tid & 63, w = tid >> 6;
  int bid = blockIdx.x, mt, nt;
  if (bid < 384) { mt = (bid >> 5) * 8 + (bid & 7); nt = (bid >> 3) & 3; }
  else           { mt = 96 + ((bid - 384) >> 2);    nt = (bid - 384) & 3; }
  int wr = (w >> 1) * 64, wc = (w & 1) * 64;
  int rr = lane & 15, kb = lane >> 4;
  f32x4 acc[4][4];
#pragma unroll
  for (int f = 0; f < 4; ++f)
#pragma unroll
    for (int q = 0; q < 4; ++q) acc[f][q] = (f32x4){0.f,0.f,0.f,0.f};

  const unsigned short* gA = encb + (size_t)mt * 128 * 2048;
  const unsigned short* gB = Web + (size_t)nt * 128 * 2048;
  int L0 = tid, L1 = tid + 256;
  size_t s0 = (size_t)(L0 & 127) * 2048 + ((L0 >> 7) << 3);
  size_t s1 = (size_t)(L1 & 127) * 2048 + ((L1 >> 7) << 3);
  int d0 = (w * 64) * 8, d1 = (w * 64 + 256) * 8;

#define STAGE_A1(kk, bf) do { \
    gload16(gA + s0 + (size_t)(kk) * 32, &As[bf][d0]); \
    gload16(gB + s0 + (size_t)(kk) * 32, &Bs[bf][d0]); \
    gload16(gA + s1 + (size_t)(kk) * 32, &As[bf][d1]); \
    gload16(gB + s1 + (size_t)(kk) * 32, &Bs[bf][d1]); \
  } while (0)

  STAGE_A1(0, 0);
  __syncthreads();
  for (int kk = 0; kk < 64; ++kk) {
    int cur = kk & 1;
    if (kk < 63) STAGE_A1(kk + 1, cur ^ 1);
    short8 af[4], bq[4];
#pragma unroll
    for (int f = 0; f < 4; ++f)
      af[f] = *(const short8*)&As[cur][((kb << 7) + wr + f * 16 + rr) * 8];
#pragma unroll
    for (int q = 0; q < 4; ++q)
      bq[q] = *(const short8*)&Bs[cur][((kb << 7) + wc + q * 16 + rr) * 8];
#pragma unroll
    for (int f = 0; f < 4; ++f)
#pragma unroll
      for (int q = 0; q < 4; ++q)
        acc[f][q] = __builtin_amdgcn_mfma_f32_16x16x32_bf16(af[f], bq[q], acc[f][q], 0, 0, 0);
    __syncthreads();
  }
#undef STAGE_A1
  int col = lane & 15, rhi = lane >> 4;
#pragma unroll
  for (int q = 0; q < 4; ++q) {
    int n = nt * 128 + wc + q * 16 + col;
    float bev = be[n];
#pragma unroll
    for (int f = 0; f < 4; ++f)
#pragma unroll
      for (int r = 0; r < 4; ++r) {
        int m = mt * 128 + wr + f * 16 + rhi * 4 + r;
        att1b[(size_t)m * 512 + n] = f2b(acc[f][q][r] + bev);
      }
  }
}

// ---- encW = enc @ B2^T: single-buffered 16KB LDS for occupancy, XCD-grouped ----
__global__ __launch_bounds__(256) void k_encw(const unsigned short* __restrict__ encb,
                      const unsigned short* __restrict__ B2, unsigned short* __restrict__ encW){
  __shared__ __align__(16) unsigned short As[4096], Bs[4096];   // 1 x (128 rows x 32 k)
  int tid = threadIdx.x, lane = tid & 63, w = tid >> 6;
  int xcd = blockIdx.x & 7, slot = blockIdx.x >> 3;
  int mtl = slot >> 4, nt = slot & 15;
  int mt = mtl * 8 + xcd;
  if (mt >= 98) return;
  int wr = (w >> 1) * 64, wc = (w & 1) * 64;
  int rr = lane & 15, kb = lane >> 4;
  f32x4 acc[4][4];
#pragma unroll
  for (int f = 0; f < 4; ++f)
#pragma unroll
    for (int q = 0; q < 4; ++q) acc[f][q] = (f32x4){0.f,0.f,0.f,0.f};

  const unsigned short* gA = encb + (size_t)mt * 128 * 2048;
  const unsigned short* gB = B2 + (size_t)nt * 128 * 2048;
  int L0 = tid, L1 = tid + 256;
  size_t s0 = (size_t)(L0 & 127) * 2048 + ((L0 >> 7) << 3);
  size_t s1 = (size_t)(L1 & 127) * 2048 + ((L1 >> 7) << 3);
  int d0 = (w * 64) * 8, d1 = (w * 64 + 256) * 8;

  for (int kk = 0; kk < 64; ++kk) {
    gload16(gA + s0 + (size_t)kk * 32, &As[d0]);
    gload16(gB + s0 + (size_t)kk * 32, &Bs[d0]);
    gload16(gA + s1 + (size_t)kk * 32, &As[d1]);
    gload16(gB + s1 + (size_t)kk * 32, &Bs[d1]);
    asm volatile("s_waitcnt vmcnt(0)" ::: "memory");
    __syncthreads();
    short8 af[4], bq[4];
#pragma unroll
    for (int f = 0; f < 4; ++f)
      af[f] = *(const short8*)&As[((kb << 7) + wr + f * 16 + rr) * 8];
#pragma unroll
    for (int q = 0; q < 4; ++q)
      bq[q] = *(const short8*)&Bs[((kb << 7) + wc + q * 16 + rr) * 8];
#pragma unroll
    for (int f = 0; f < 4; ++f)
#pragma unroll
      for (int q = 0; q < 4; ++q)
        acc[f][q] = __builtin_amdgcn_mfma_f32_16x16x32_bf16(af[f], bq[q], acc[f][q], 0, 0, 0);
    __syncthreads();
  }
  int col = lane & 15, rhi = lane >> 4;
#pragma unroll
  for (int q = 0; q < 4; ++q) {
    int n = nt * 128 + wc + q * 16 + col;
#pragma unroll
    for (int f = 0; f < 4; ++f)
#pragma unroll
      for (int r = 0; r < 4; ++r) {
        int m = mt * 128 + wr + f * 16 + rhi * 4 + r;
        encW[(size_t)m * 2048 + n] = f2b(acc[f][q][r]);
      }
  }
}

// ---- step1lite: MFMA wave GEMM. waves: [0,32)=att2, [32,160)=gates_he (R11-proven) ----
__global__ __launch_bounds__(256) void k_step1lite(const unsigned short* __restrict__ hx,
                       const unsigned short* __restrict__ B1,
                       const float* __restrict__ bd, const float* __restrict__ bih, const float* __restrict__ bhh,
                       float* __restrict__ att2f, float* __restrict__ geh){
  int w = threadIdx.x >> 6, lane = threadIdx.x & 63;
  int omega = blockIdx.x * 4 + w;
  int rr = lane & 15, kb8 = (lane >> 4) * 8;
  const unsigned short* pb; int kIt;
  if (omega < 32) { pb = B1 + (size_t)(omega * 16 + rr) * 1024 + kb8; kIt = 16; }
  else            { pb = B1 + (size_t)(512 + (omega - 32) * 16 + rr) * 1024 + kb8; kIt = 32; }
  const unsigned short* pa0 = hx + (size_t)rr * 1024 + kb8;
  f32x4 acc[4];
#pragma unroll
  for (int f = 0; f < 4; ++f) acc[f] = (f32x4){0.f,0.f,0.f,0.f};
#pragma unroll 4
  for (int kk = 0; kk < kIt; ++kk) {
    short8 bfr = *(const short8*)(pb + kk * 32);
#pragma unroll
    for (int f = 0; f < 4; ++f) {
      short8 afr = *(const short8*)(pa0 + (size_t)f * 16384 + kk * 32);
      acc[f] = __builtin_amdgcn_mfma_f32_16x16x32_bf16(afr, bfr, acc[f], 0, 0, 0);
    }
  }
  int col = lane & 15, rhi = lane >> 4;
  if (omega < 32) {
    int n = omega * 16 + col; float bv = bd[n];
#pragma unroll
    for (int f = 0; f < 4; ++f)
#pragma unroll
      for (int r = 0; r < 4; ++r) { int b = f * 16 + rhi * 4 + r; att2f[(size_t)b * 512 + n] = acc[f][r] + bv; }
  } else {
    int j = (omega - 32) * 16 + col; int g = (j & 3) * 512 + (j >> 2);
    float bv = bih[g] + bhh[g];
#pragma unroll
    for (int f = 0; f < 4; ++f)
#pragma unroll
      for (int r = 0; r < 4; ++r) { int b = f * 16 + rhi * 4 + r; geh[(size_t)b * 2048 + j] = acc[f][r] + bv; }
  }
}

__global__ __launch_bounds__(256) void k_scores(int t, const unsigned short* __restrict__ att1b, const float* __restrict__ att2f,
                        const float* __restrict__ wf, const float* __restrict__ bfp,
                        const int* __restrict__ meta, float* __restrict__ sc){
  int b = blockIdx.y, pc = blockIdx.x;
  if (b >= meta[128 + t]) return;
  int tid = threadIdx.x, lane = tid & 63, w = tid >> 6;
  float wfr[8], a2[8];
#pragma unroll
  for (int j = 0; j < 8; ++j) { wfr[j] = wf[lane * 8 + j]; a2[j] = att2f[(size_t)b * 512 + lane * 8 + j]; }
  float bf0 = bfp[0];
  for (int pi = w; pi < 49; pi += 4) {
    int p = pc * 49 + pi;
    short8 av = *(const short8*)(att1b + ((size_t)(b * 196 + p)) * 512 + lane * 8);
    float s = 0.f;
#pragma unroll
    for (int j = 0; j < 8; ++j) s += tanhf_fast(b2f((unsigned short)av[j]) + a2[j]) * wfr[j];
#pragma unroll
    for (int off = 32; off; off >>= 1) s += __shfl_xor(s, off);
    if (lane == 0) sc[(size_t)b * 196 + p] = s + bf0;
  }
}

// ---- k_gc: softmax + gates_ctx = alpha@encW + geh + cell + hh + emb (R11-proven) ----
__global__ __launch_bounds__(256) void k_gc(int t, const float* __restrict__ sc,
                      const unsigned short* __restrict__ encW, const float* __restrict__ geh,
                      const float* __restrict__ Wemb, const int* __restrict__ meta,
                      float* __restrict__ out, float* __restrict__ cbuf,
                      unsigned short* __restrict__ hx, unsigned short* __restrict__ hh){
  int b = blockIdx.y, ch = blockIdx.x;
  int tid = threadIdx.x, lane = tid & 63, w = tid >> 6;
  int na = meta[128 + t];
  __shared__ float sal[200];
  __shared__ float red[256];
  __shared__ float part[4][512];
  __shared__ float gt[512];

  if (b < na) {
    float v = (tid < 196) ? sc[(size_t)b * 196 + tid] : -3.0e38f;
    red[tid] = v; __syncthreads();
    for (int s = 128; s; s >>= 1) { if (tid < s) red[tid] = fmaxf(red[tid], red[tid + s]); __syncthreads(); }
    float mx = red[0]; __syncthreads();
    float ex = (tid < 196) ? __expf(v - mx) : 0.f;
    red[tid] = ex; __syncthreads();
    for (int s = 128; s; s >>= 1) { if (tid < s) red[tid] += red[tid + s]; __syncthreads(); }
    float inv = 1.0f / red[0];
    __syncthreads();
    if (tid < 196) {
      float al = ex * inv;
      sal[tid] = al;
      if (ch == 0) out[PRED_ELEMS + ((size_t)b * 30 + t) * 196 + tid] = al;
    }
    __syncthreads();

    const unsigned short* ep = encW + ((size_t)b * 196) * 2048 + ch * 512 + lane * 8;
    float s8[8];
#pragma unroll
    for (int j = 0; j < 8; ++j) s8[j] = 0.f;
#pragma unroll 7
    for (int i = 0; i < 49; ++i) {
      int p = w + i * 4;
      short8 vv = *(const short8*)(ep + (size_t)p * 2048);
      float a = sal[p];
#pragma unroll
      for (int j = 0; j < 8; ++j) s8[j] += a * b2f((unsigned short)vv[j]);
    }
#pragma unroll
    for (int j = 0; j < 8; ++j) part[w][lane * 8 + j] = s8[j];
    __syncthreads();
    int j0 = tid * 2;
    gt[j0]     = part[0][j0] + part[1][j0] + part[2][j0] + part[3][j0]
               + geh[(size_t)b * 2048 + ch * 512 + j0];
    gt[j0 + 1] = part[0][j0 + 1] + part[1][j0 + 1] + part[2][j0 + 1] + part[3][j0 + 1]
               + geh[(size_t)b * 2048 + ch * 512 + j0 + 1];
    __syncthreads();

    if (tid < 128) {
      int d = ch * 128 + tid;
      float ig = gt[tid * 4 + 0];
      float fg = gt[tid * 4 + 1];
      float gg = gt[tid * 4 + 2];
      float og = gt[tid * 4 + 3];
      float c0 = cbuf[(size_t)b * 512 + d];
      float ct = sigm(fg) * c0 + sigm(ig) * tanhf_fast(gg);
      float ht = sigm(og) * tanhf_fast(ct);
      cbuf[(size_t)b * 512 + d] = ct;
      unsigned short hb = f2b(ht);
      hx[(size_t)b * 1024 + d] = hb;
      hh[((size_t)t * 64 + b) * 512 + d] = hb;
      int cap = meta[160 + b * 31 + t + 1];
      hx[(size_t)b * 1024 + 512 + d] = f2b(Wemb[(size_t)cap * 512 + d]);
    }
  } else {
    if (tid < 128) {
      int d = ch * 128 + tid;
      unsigned short hold = hx[(size_t)b * 1024 + d];
      hh[((size_t)t * 64 + b) * 512 + d] = hold;
      int cap = meta[160 + b * 31 + t + 1];
      hx[(size_t)b * 1024 + 512 + d] = f2b(Wemb[(size_t)cap * 512 + d]);
    }
  }
}

// ---- pred: all-steps batched GEMM hh[1920x512] @ Wfcb^T -> out (masked) ----
__global__ __launch_bounds__(256) void k_pred(const unsigned short* __restrict__ hh,
                      const unsigned short* __restrict__ Wfcb, const float* __restrict__ bfc,
                      const int* __restrict__ meta, float* __restrict__ out){
  __shared__ __align__(16) unsigned short As[2][4096], Bs[2][4096];
  int tid = threadIdx.x, lane = tid & 63, w = tid >> 6;
  int mt = blockIdx.x % 15, nt = blockIdx.x / 15;   // 15 x 79
  int wr = (w >> 1) * 64, wc = (w & 1) * 64;
  int rr = lane & 15, kb = lane >> 4;
  f32x4 acc[4][4];
#pragma unroll
  for (int f = 0; f < 4; ++f)
#pragma unroll
    for (int q = 0; q < 4; ++q) acc[f][q] = (f32x4){0.f,0.f,0.f,0.f};

  const unsigned short* gA = hh + (size_t)mt * 128 * 512;
  int L0 = tid, L1 = tid + 256;
  size_t sa0 = (size_t)(L0 & 127) * 512 + ((L0 >> 7) << 3);
  size_t sa1 = (size_t)(L1 & 127) * 512 + ((L1 >> 7) << 3);
  int br0 = nt * 128 + (L0 & 127); if (br0 > 10015) br0 = 10015;
  int br1 = nt * 128 + (L1 & 127); if (br1 > 10015) br1 = 10015;
  size_t sb0 = (size_t)br0 * 512 + ((L0 >> 7) << 3);
  size_t sb1 = (size_t)br1 * 512 + ((L1 >> 7) << 3);
  int d0 = (w * 64) * 8, d1 = (w * 64 + 256) * 8;

#define STAGE_P(kk, bf) do { \
    gload16(gA + sa0 + (size_t)(kk) * 32, &As[bf][d0]); \
    gload16(Wfcb + sb0 + (size_t)(kk) * 32, &Bs[bf][d0]); \
    gload16(gA + sa1 + (size_t)(kk) * 32, &As[bf][d1]); \
    gload16(Wfcb + sb1 + (size_t)(kk) * 32, &Bs[bf][d1]); \
  } while (0)

  STAGE_P(0, 0);
  __syncthreads();
  for (int kk = 0; kk < 16; ++kk) {
    int cur = kk & 1;
    if (kk < 15) STAGE_P(kk + 1, cur ^ 1);
    short8 af[4], bq[4];
#pragma unroll
    for (int f = 0; f < 4; ++f)
      af[f] = *(const short8*)&As[cur][((kb << 7) + wr + f * 16 + rr) * 8];
#pragma unroll
    for (int q = 0; q < 4; ++q)
      bq[q] = *(const short8*)&Bs[cur][((kb << 7) + wc + q * 16 + rr) * 8];
#pragma unroll
    for (int f = 0; f < 4; ++f)
#pragma unroll
      for (int q = 0; q < 4; ++q)
        acc[f][q] = __builtin_amdgcn_mfma_f32_16x16x32_bf16(af[f], bq[q], acc[f][q], 0, 0, 0);
    __syncthreads();
  }
#undef STAGE_P
  int col = lane & 15, rhi = lane >> 4;
  int tt = mt * 2 + (wr >> 6);
  int na = meta[128 + tt];
#pragma unroll
  for (int q = 0; q < 4; ++q) {
    int n = nt * 128 + wc + q * 16 + col;
    if (n >= 10000) continue;
    float bv = bfc[n];
#pragma unroll
    for (int f = 0; f < 4; ++f)
#pragma unroll
      for (int r = 0; r < 4; ++r) {
        int b = f * 16 + rhi * 4 + r;
        if (b < na) out[(size_t)b * 300000 + (size_t)tt * 10000 + n] = acc[f][q][r] + bv;
      }
  }
}

extern "C" void kernel_launch(void* const* d_in, const int* in_sizes, int n_in,
                              void* d_out, int out_size, void* d_ws, size_t ws_size,
                              hipStream_t stream) {
  (void)in_sizes; (void)n_in; (void)ws_size;
  const float* enc  = (const float*)d_in[0];
  const int*   caps = (const int*)d_in[1];
  const int*   lens = (const int*)d_in[2];
  const float* Wemb = (const float*)d_in[3];
  const float* We   = (const float*)d_in[4];
  const float* be   = (const float*)d_in[5];
  const float* Wd   = (const float*)d_in[6];
  const float* bd   = (const float*)d_in[7];
  const float* wf   = (const float*)d_in[8];
  const float* bf   = (const float*)d_in[9];
  const float* Wih  = (const float*)d_in[10];
  const float* bih  = (const float*)d_in[11];
  const float* Whh  = (const float*)d_in[12];
  const float* bhh  = (const float*)d_in[13];
  const float* Wfc  = (const float*)d_in[14];
  const float* bfc  = (const float*)d_in[15];
  const float* Wh0  = (const float*)d_in[16];
  const float* bh0  = (const float*)d_in[17];
  const float* Wc0  = (const float*)d_in[18];
  const float* bc0  = (const float*)d_in[19];

  char* ws = (char*)d_ws;
  unsigned short* encb  = (unsigned short*)(ws + OFF_ENC);
  unsigned short* att1b = (unsigned short*)(ws + OFF_ATT1);
  unsigned short* B1    = (unsigned short*)(ws + OFF_B1);
  unsigned short* Wfcb  = (unsigned short*)(ws + OFF_WFC);
  unsigned short* Web   = (unsigned short*)(ws + OFF_WEB);
  unsigned short* B0    = (unsigned short*)(ws + OFF_B0);
  unsigned short* hh    = (unsigned short*)(ws + OFF_HH);
  unsigned short* B2    = (unsigned short*)(ws + OFF_B2);
  unsigned short* hx    = (unsigned short*)(ws + OFF_HX);
  float*          cbuf  = (float*)(ws + OFF_C);
  float*          att2f = (float*)(ws + OFF_ATT2);
  float*          geh   = (float*)(ws + OFF_GEH);
  float*          sc    = (float*)(ws + OFF_SC);
  unsigned short* ctxb  = (unsigned short*)(ws + OFF_CTX);
  int*            meta  = (int*)(ws + OFF_META);
  unsigned short* encWb = (unsigned short*)(ws + OFF_ENCW);
  unsigned short* meanb = ctxb;   // setup-time only
  float* out = (float*)d_out;

  hipMemsetAsync(d_out, 0, (size_t)out_size * sizeof(float), stream);
  k_meta<<<1, 64, 0, stream>>>(caps, lens, meta);
  k_encg<<<12544, 256, 0, stream>>>(enc, meta, encb);
  k_wconv<<<16160, 256, 0, stream>>>(We, Wh0, Wc0, Wd, Whh, Wih, Wfc, Web, B0, B1, Wfcb, B2);
  k_mean<<<dim3(4, 64), 256, 0, stream>>>(encb, meanb);
  k_h0c0<<<16, 256, 0, stream>>>(meanb, B0, bh0, bc0, hx, cbuf);
  k_emb0<<<64, 256, 0, stream>>>(Wemb, meta, hx);
  k_att1<<<392, 256, 0, stream>>>(encb, Web, be, att1b);
  k_encw<<<1664, 256, 0, stream>>>(encb, B2, encWb);

  for (int t = 0; t < 30; ++t) {
    k_step1lite<<<40, 256, 0, stream>>>(hx, B1, bd, bih, bhh, att2f, geh);
    k_scores<<<dim3(4, 64), 256, 0, stream>>>(t, att1b, att2f, wf, bf, meta, sc);
    k_gc<<<dim3(4, 64), 256, 0, stream>>>(t, sc, encWb, geh, Wemb, meta, out, cbuf, hx, hh);
  }
  k_pred<<<1185, 256, 0, stream>>>(hh, Wfcb, bfc, meta, out);
}